// Round 3
// baseline (4286.734 us; speedup 1.0000x reference)
//
#include <hip/hip_runtime.h>

typedef __bf16 bf16;
typedef bf16 bf16x8 __attribute__((ext_vector_type(8)));
typedef bf16 bf16x4 __attribute__((ext_vector_type(4)));
typedef float f32x4 __attribute__((ext_vector_type(4)));
typedef float f32x2 __attribute__((ext_vector_type(2)));

#define MFMA16(a,b,c) __builtin_amdgcn_mfma_f32_16x16x32_bf16((a),(b),(c),0,0,0)

#define B_N 256
#define T_N 512
#define H_N 768
#define WROW 776      // 768 + 8 pad (bf16 elems)

// ---- device-global scratch (BSS) ----
__device__ float    g_ctrl[B_N * T_N];          // 512 KB
__device__ bf16     g_hbuf[2 * B_N * H_N];      // 768 KB (bf16 h exchange, intra-XCD L2)
__device__ unsigned g_flag[256 * 64];           // per-(block,set) flag, 128B apart
__device__ unsigned g_members[8 * 32];          // XCD roster -> blockIdx table
__device__ unsigned g_roster[8];
__device__ unsigned g_sync;

__device__ __forceinline__ float sigmoidf_(float x){ return 1.f/(1.f+__expf(-x)); }
__device__ __forceinline__ float tanhf_(float x){
  float e = __expf(-2.f*fabsf(x));
  float t = (1.f-e)/(1.f+e);
  return copysignf(t, x);
}
__device__ __forceinline__ float softplusf_(float x){
  return x > 20.f ? x : log1pf(__expf(x));
}
__device__ __forceinline__ bf16x8 ld_bf8(const float* p){
  f32x4 a = *(const f32x4*)p;
  f32x4 b = *(const f32x4*)(p + 4);
  bf16x8 v;
  v[0]=(bf16)a[0]; v[1]=(bf16)a[1]; v[2]=(bf16)a[2]; v[3]=(bf16)a[3];
  v[4]=(bf16)b[0]; v[5]=(bf16)b[1]; v[6]=(bf16)b[2]; v[7]=(bf16)b[3];
  return v;
}

__global__ void k_zero() {
  const int tid = threadIdx.x;
  for (int i = tid; i < 256*64; i += 256) g_flag[i] = 0u;
  if (tid < 256) g_members[tid] = 0u;   // fallback: block 0's flags (always advance)
  if (tid < 8)   g_roster[tid] = 0u;
  if (tid == 0)  g_sync = 0u;
}

// ---------------- kernel A: causal encoder Z + ctrl term (unchanged) ----------------
__global__ __launch_bounds__(256) void k_encode(
    const float* __restrict__ Xm, const float* __restrict__ Xc,
    const float* __restrict__ Aw,
    const float* __restrict__ ew1, const float* __restrict__ eb1,
    const float* __restrict__ ew2, const float* __restrict__ eb2,
    const float* __restrict__ nw,  const float* __restrict__ nb,
    const float* __restrict__ cw,  const float* __restrict__ cb,
    float* __restrict__ Zout)
{
  __shared__ float sA[16][16], sE1[16][32], sE2[16][16], sNW[16][32];
  __shared__ float sEB1[16], sEB2[16], sNB[16];
  __shared__ float sCW[768][16];
  __shared__ float sCB[768];
  const int tid = threadIdx.x;
  for (int i = tid; i < 256; i += 256) sA[i>>4][i&15] = Aw[i];
  for (int i = tid; i < 512; i += 256) sE1[i>>5][i&31] = ew1[i];
  for (int i = tid; i < 256; i += 256) sE2[i>>4][i&15] = ew2[i];
  for (int i = tid; i < 512; i += 256) sNW[i>>5][i&31] = nw[i];
  if (tid < 16) { sEB1[tid]=eb1[tid]; sEB2[tid]=eb2[tid]; sNB[tid]=nb[tid]; }
  for (int i = tid; i < 768*16; i += 256) sCW[i>>4][i&15] = cw[i];
  for (int i = tid; i < 768; i += 256) sCB[i] = cb[i];
  __syncthreads();
  const int idx = blockIdx.x*256 + tid;           // flat (b*T + t)
  const float* xmp = Xm + (size_t)idx*16;
  const float* xcp = Xc + (size_t)idx*16;
  float xm[16], xc[16];
  #pragma unroll
  for (int j=0;j<4;j++){
    *(f32x4*)&xm[j*4] = *(const f32x4*)(xmp + j*4);
    *(f32x4*)&xc[j*4] = *(const f32x4*)(xcp + j*4);
  }
  float snd[16], rcv[16];
  #pragma unroll
  for (int i=0;i<16;i++){
    float s=0.f, r=0.f;
    #pragma unroll
    for (int j=0;j<16;j++){ s += xm[j]*sA[i][j]; r += xm[j]*sA[j][i]; }
    snd[i]=s; rcv[i]=r;
  }
  float he[16];
  #pragma unroll
  for (int i=0;i<16;i++){
    float a = sEB1[i];
    #pragma unroll
    for (int k=0;k<16;k++) a += snd[k]*sE1[i][k];
    #pragma unroll
    for (int k=0;k<16;k++) a += rcv[k]*sE1[i][16+k];
    he[i] = fmaxf(a, 0.f);
  }
  float he2[16];
  #pragma unroll
  for (int i=0;i<16;i++){
    float a = sEB2[i];
    #pragma unroll
    for (int k=0;k<16;k++) a += he[k]*sE2[i][k];
    he2[i] = fmaxf(a, 0.f);
  }
  float* zp = Zout + (size_t)idx*16;
  #pragma unroll
  for (int m=0;m<16;m++){
    float a = sNB[m];
    #pragma unroll
    for (int k=0;k<16;k++) a += xm[k]*sNW[m][k];
    #pragma unroll
    for (int k=0;k<16;k++) a += he2[k]*sNW[m][16+k];
    zp[m] = fmaxf(a, 0.f);
  }
  float cs = 0.f;
  for (int i=0;i<768;i++){
    float a = sCB[i];
    #pragma unroll
    for (int k=0;k<16;k++) a += xc[k]*sCW[i][k];
    cs += fmaxf(a, 0.f);
  }
  g_ctrl[idx] = cs * 0.3f;
}

// ---------------- kernel B: adstock scan + hill + gru-input (unchanged) ----------------
__global__ __launch_bounds__(64) void k_adstock(
    const float* __restrict__ Xm, const float* __restrict__ alpha,
    const float* __restrict__ hill_a, const float* __restrict__ hill_g,
    float* __restrict__ Zio, float* __restrict__ hill_out)
{
  const int gid = blockIdx.x*64 + threadIdx.x;   // (b, m)
  const int b = gid >> 4, m = gid & 15;
  float a  = fminf(fmaxf(alpha[m],  0.f),  1.f);
  float ha = fminf(fmaxf(hill_a[m], 0.1f), 3.f);
  float hg = fminf(fmaxf(hill_g[m], 0.1f), 2.f);
  float gpow = __powf(hg, ha);
  const float* xp = Xm + (size_t)b*T_N*16 + m;
  float prev = 0.f, cmax = 0.f;
  for (int t=0;t<T_N;t++){ float x = xp[(size_t)t*16]; prev = x + a*prev; cmax = fmaxf(cmax, prev); }
  cmax = fmaxf(cmax, 1e-6f);
  float inv = 1.f/cmax;
  prev = 0.f;
  float* zp  = Zio      + (size_t)b*T_N*16 + m;
  float* hp  = hill_out + (size_t)b*T_N*16 + m;
  for (int t=0;t<T_N;t++){
    float x = xp[(size_t)t*16];
    prev = x + a*prev;
    float xn  = fmaxf(prev*inv, 0.f);
    float num = __powf(xn, ha);
    float h   = num / (num + gpow + 1e-8f);
    float z   = zp[(size_t)t*16];
    hp[(size_t)t*16] = h;
    zp[(size_t)t*16] = h + z;
  }
}

// ---------------- kernel C: persistent GRU, 3 compute + 1 service wave ----------------
// Waves 0..2 = compute (full-K MFMA for 2 row-tiles each: one register tile +
// one LDS tile); wave 3 = service: processes the PREVIOUS phase's D (gates ->
// publish -> wave-local vmcnt -> flag -> hidden flag-poll -> LDS token ->
// deferred epilogue). One __syncthreads per phase. Compute waves check the
// token and usually skip the global poll; the 24-deep h register volley uses a
// counted vmcnt(16/8/0) ladder so L2 latency hides under the MFMA stream.
// sGH2/sGIN are phase-double-buffered. Proven protocol invariants kept:
// plain-store publish -> vmcnt drain -> relaxed MALL flag; sc0 volley reads.
// Local row layout (per 24-dim slice j0=p*24):
//   0..23 r | 24..47 z | 48..71 n | 72..87 head | 88..95 zero
// Tiles T0..T5 of 16 rows; wave w: reg tile T(2w) (cols w*32..+15),
// LDS tile T(2w+1) (cols w*32+16..+31). Input x folded into T0,T1,T2;
// kept separate (sGIN) for T3,T4; none for T5.
__device__ __forceinline__ bool poll_flags(unsigned midx, unsigned val) {
  int tries = 0; bool ok = true;
  for (;;) {
    unsigned v = __hip_atomic_load(&g_flag[midx], __ATOMIC_RELAXED, __HIP_MEMORY_SCOPE_AGENT);
    if (__ballot(v >= val) == ~0ull) break;
    if (++tries > (1<<18)) { ok = false; break; }   // fail-visible, never hang
    if (tries > 8) __builtin_amdgcn_s_sleep(1);
  }
  __builtin_amdgcn_fence(__ATOMIC_ACQUIRE, "workgroup");
  return ok;
}

// NOTE: gfx950 assembler requires offset: BEFORE the cache flag (off offset:N sc0)
#define HL(i, OFF) asm volatile("global_load_dwordx4 %0, %1, off offset:" OFF " sc0" \
      : "=v"(hf[i]) : "v"(hsrc) : "memory")

__global__ __launch_bounds__(256, 1) void k_gru(
    const float* __restrict__ Xc,
    const float* __restrict__ Wih, const float* __restrict__ Whh,
    const float* __restrict__ bih, const float* __restrict__ bhh,
    const float* __restrict__ wraww, const float* __restrict__ wrawb,
    const float* __restrict__ regemb, const float* __restrict__ bias,
    const float* __restrict__ h0,
    float* __restrict__ hillZ,       // = outw region (read until step t, then w_pos)
    float* __restrict__ hill,        // = outc region (read hill, overwrite contrib)
    float* __restrict__ outy)
{
  __shared__ __align__(16) bf16 sW2[48*WROW];     // 74,496 B : LDS tiles T1,T3,T5
  __shared__ __align__(16) float sGH2[2][16][100];// 12,800 B : D staging, phase dbuf
  __shared__ __align__(16) float sGIN[2][16][32]; //  4,096 B : n-gate input part, dbuf
  __shared__ __align__(16) float sHm[32][28];     //  3,584 B : f32 master h (both sets)
  __shared__ __align__(16) float sBih[72], sBhh[72]; // 576 B
  __shared__ float sWrb[16];
  __shared__ float sScal[2];
  __shared__ unsigned sGP[2];
  __shared__ unsigned sTok[2];                    // pre-verified flag tokens per set

  const int tid = threadIdx.x;
  const int wave = tid >> 6, lane = tid & 63;
  const int quad = lane >> 4, l16 = lane & 15;

  // runtime group discovery: g = physical XCD
  if (tid == 0) {
    unsigned x;
    asm volatile("s_getreg_b32 %0, hwreg(HW_REG_XCC_ID, 0, 32)" : "=s"(x));
    x &= 7u;
    unsigned slot = __hip_atomic_fetch_add(&g_roster[x], 1u,
                        __ATOMIC_RELAXED, __HIP_MEMORY_SCOPE_AGENT);
    if (slot < 32u)
      __hip_atomic_store(&g_members[x*32u + slot], (unsigned)blockIdx.x,
                         __ATOMIC_RELAXED, __HIP_MEMORY_SCOPE_AGENT);
    sGP[0] = x; sGP[1] = slot & 31u;
    sTok[0] = 0u; sTok[1] = 0u;
    __hip_atomic_fetch_add(&g_sync, 1u, __ATOMIC_RELEASE, __HIP_MEMORY_SCOPE_AGENT);
    int tries = 0;
    while (__hip_atomic_load(&g_sync, __ATOMIC_ACQUIRE, __HIP_MEMORY_SCOPE_AGENT) < 256u) {
      if (++tries > (1<<20)) break;
      __builtin_amdgcn_s_sleep(1);
    }
  }
  __syncthreads();
  const int g = (int)sGP[0], p = (int)sGP[1];
  const int j0 = p*24;
  const int s_own = (p >= 16) ? 1 : 0;
  const int bqL = p & 15;
  const int bq = g*32 + p;
  const unsigned member = __hip_atomic_load(&g_members[g*32 + (lane & 31)],
                              __ATOMIC_RELAXED, __HIP_MEMORY_SCOPE_AGENT);
  const unsigned midx0 = member * 64u;
  const unsigned myflag = (unsigned)blockIdx.x * 64u;

  // ---- stage LDS weight tiles T1,T3,T5: rows rl<16 -> L=16+rl; <32 -> 32+rl; else 48+rl
  for (int c = tid; c < 48*192; c += 256) {
    int rl = c / 192, off = (c - rl*192)*4;
    int L = (rl < 16) ? (16 + rl) : ((rl < 32) ? (32 + rl) : (48 + rl));
    f32x4 w;
    if (L < 72)      w = *(const f32x4*)&Whh[(size_t)((L/24)*768 + j0 + (L%24))*768 + off];
    else if (L < 88) w = *(const f32x4*)&wraww[(size_t)(L-72)*768 + off];
    else             { w[0]=0.f; w[1]=0.f; w[2]=0.f; w[3]=0.f; }
    bf16x4 v; v[0]=(bf16)w[0]; v[1]=(bf16)w[1]; v[2]=(bf16)w[2]; v[3]=(bf16)w[3];
    *(bf16x4*)&sW2[rl*WROW + off] = v;
  }
  if (tid < 72) {
    int grow = (tid/24)*768 + j0 + (tid%24);
    sBih[tid] = bih[grow];
    sBhh[tid] = bhh[grow];
  }
  if (tid >= 128 && tid < 144) sWrb[tid-128] = wrawb[tid-128];
  if (wave == 0) {
    float sacc = 0.f;
    for (int k = lane; k < 768; k += 64) sacc += regemb[k];  // reg_emb[0]
    #pragma unroll
    for (int off = 32; off; off >>= 1) sacc += __shfl_xor(sacc, off, 64);
    if (lane == 0) { sScal[0] = 0.3f*sacc; sScal[1] = bias[0]; }
  }

  // ---- per-wave t-invariant register weights ----
  bf16x8 bw[24];                 // reg tile T(2*wave), full K
  bf16x8 wf0, wf1, wfg;
  #pragma unroll
  for (int i = 0; i < 8; i++) { wf0[i]=(bf16)0.f; wf1[i]=(bf16)0.f; wfg[i]=(bf16)0.f; }
  if (wave < 3) {
    const int L = wave*32 + l16;
    const float* rowA = (L < 72)
        ? Whh + (size_t)((L/24)*768 + j0 + (L%24))*768
        : wraww + (size_t)(L-72)*768;
    #pragma unroll
    for (int kk = 0; kk < 24; kk++) bw[kk] = ld_bf8(rowA + kk*32 + quad*8);
    if (wave == 0) {
      const int La = l16, Lb = 16 + l16;
      wf0 = ld_bf8(Wih + (size_t)((La/24)*768 + j0 + (La%24))*32 + quad*8);
      wf1 = ld_bf8(Wih + (size_t)((Lb/24)*768 + j0 + (Lb%24))*32 + quad*8);
    } else if (wave == 1) {
      const int La = 32 + l16, Lb = 48 + l16;
      wf0 = ld_bf8(Wih + (size_t)((La/24)*768 + j0 + (La%24))*32 + quad*8);
      wfg = ld_bf8(Wih + (size_t)((Lb/24)*768 + j0 + (Lb%24))*32 + quad*8);
    } else {
      const int Lb = 64 + l16;
      if (Lb < 72)
        wfg = ld_bf8(Wih + (size_t)((Lb/24)*768 + j0 + (Lb%24))*32 + quad*8);
    }
  }

  // ---- init h (parity 0): f32 master + bf16 publish ----
  {
    unsigned* hb = (unsigned*)g_hbuf;
    for (int e = tid; e < 384; e += 256) {
      int b = e/12, j = (e - b*12)*2;
      float f0 = h0[j0+j], f1 = h0[j0+j+1];
      sHm[b][j] = f0; sHm[b][j+1] = f1;
      union { bf16 h[2]; unsigned u; } pk;
      pk.h[0] = (bf16)f0; pk.h[1] = (bf16)f1;
      hb[((size_t)(g*32+b)*H_N + j0 + j) >> 1] = pk.u;
    }
  }
  __syncthreads();   // drains init publishes + LDS staging
  if (tid == 0) {
    __hip_atomic_store(&g_flag[myflag],      1u, __ATOMIC_RELAXED, __HIP_MEMORY_SCOPE_AGENT);
    __hip_atomic_store(&g_flag[myflag + 32], 1u, __ATOMIC_RELAXED, __HIP_MEMORY_SCOPE_AGENT);
  }
  const float regt = sScal[0], bias0 = sScal[1];

  // service-wave epilogue state
  float wp0_r = 0.f, hl0_r = 0.f, ct0_r = 0.f;
  float hl_pf = 0.f, ct_pf = 0.f;
  if (wave == 3 && lane < 16) {
    hl_pf = hill[(size_t)bq*T_N*16 + lane];
    if (lane == 0) ct_pf = g_ctrl[(size_t)bq*T_N];
  }

  // compute-wave x prologue (phase 0 = (t0, set0))
  f32x4 xf0, xf1;
  xf0[0]=0.f; xf0[1]=0.f; xf0[2]=0.f; xf0[3]=0.f; xf1 = xf0;
  if (wave < 3) {
    const int gb0 = g*32 + l16;
    const float* srcx = (quad < 2)
        ? hillZ + (size_t)gb0*T_N*16 + quad*8
        : Xc    + (size_t)gb0*T_N*16 + (quad-2)*8;
    xf0 = *(const f32x4*)srcx;
    xf1 = *(const f32x4*)(srcx + 4);
  }
  const bf16* wlds = &sW2[(size_t)(wave*16 + l16)*WROW + quad*8];

  #pragma unroll 1
  for (int k = 0; k <= 2*T_N; k++) {
    const int t = k >> 1, s = k & 1;
    if (wave < 3) {
      if (k < 2*T_N) {
        // ---- token check / poll ----
        {
          unsigned tok = sTok[s];
          if (tok < (unsigned)(t + 1))
            poll_flags(midx0 + (unsigned)(s*32), (unsigned)(t + 1));
          else
            __builtin_amdgcn_fence(__ATOMIC_ACQUIRE, "workgroup");
        }
        const bf16* hsrc = g_hbuf + (size_t)(t&1)*B_N*H_N
                         + (size_t)(g*32 + s*16 + l16)*H_N + quad*8;
        // x loads for NEXT phase (issued first; counted in the ladder)
        f32x4 xn0, xn1;
        {
          const int sn = s ^ 1;
          int tn = s ? (t + 1) : t; if (tn >= T_N) tn = T_N - 1;
          const int gbn = g*32 + sn*16 + l16;
          const float* srcx = (quad < 2)
              ? hillZ + ((size_t)gbn*T_N + tn)*16 + quad*8
              : Xc    + ((size_t)gbn*T_N + tn)*16 + (quad-2)*8;
          asm volatile("global_load_dwordx4 %0, %2, off\n\t"
                       "global_load_dwordx4 %1, %2, off offset:16"
                       : "=v"(xn0), "=v"(xn1) : "v"(srcx) : "memory");
        }
        // h volley: 24 sc0 loads, outstanding = 26 (x2 + h24)
        bf16x8 hf[24];
        HL(0,"0");    HL(1,"64");   HL(2,"128");  HL(3,"192");
        HL(4,"256");  HL(5,"320");  HL(6,"384");  HL(7,"448");
        HL(8,"512");  HL(9,"576");  HL(10,"640"); HL(11,"704");
        HL(12,"768"); HL(13,"832"); HL(14,"896"); HL(15,"960");
        HL(16,"1024");HL(17,"1088");HL(18,"1152");HL(19,"1216");
        HL(20,"1280");HL(21,"1344");HL(22,"1408");HL(23,"1472");
        // input MFMAs from last phase's x (independent of the volley)
        bf16x8 ax;
        ax[0]=(bf16)xf0[0]; ax[1]=(bf16)xf0[1]; ax[2]=(bf16)xf0[2]; ax[3]=(bf16)xf0[3];
        ax[4]=(bf16)xf1[0]; ax[5]=(bf16)xf1[1]; ax[6]=(bf16)xf1[2]; ax[7]=(bf16)xf1[3];
        f32x4 az; az[0]=0.f; az[1]=0.f; az[2]=0.f; az[3]=0.f;
        f32x4 a0e=az, a0o=az, a1e=az, a1o=az, gi=az;
        if (wave == 0)      { a0e = MFMA16(ax, wf0, a0e); a1e = MFMA16(ax, wf1, a1e); }
        else if (wave == 1) { a0e = MFMA16(ax, wf0, a0e); gi  = MFMA16(ax, wfg, gi);  }
        else                { gi  = MFMA16(ax, wfg, gi); }
        // ---- counted vmcnt ladder: L2 latency hides under MFMA ----
        asm volatile("s_waitcnt vmcnt(16)"
          : "+v"(hf[0]),"+v"(hf[1]),"+v"(hf[2]),"+v"(hf[3]),
            "+v"(hf[4]),"+v"(hf[5]),"+v"(hf[6]),"+v"(hf[7]) :: "memory");
        #pragma unroll
        for (int kk = 0; kk < 8; kk += 2) {
          a0e = MFMA16(hf[kk],   bw[kk],   a0e);
          a1e = MFMA16(hf[kk],   *(const bf16x8*)&wlds[kk*32],     a1e);
          a0o = MFMA16(hf[kk+1], bw[kk+1], a0o);
          a1o = MFMA16(hf[kk+1], *(const bf16x8*)&wlds[(kk+1)*32], a1o);
        }
        asm volatile("s_waitcnt vmcnt(8)"
          : "+v"(hf[8]),"+v"(hf[9]),"+v"(hf[10]),"+v"(hf[11]),
            "+v"(hf[12]),"+v"(hf[13]),"+v"(hf[14]),"+v"(hf[15]) :: "memory");
        #pragma unroll
        for (int kk = 8; kk < 16; kk += 2) {
          a0e = MFMA16(hf[kk],   bw[kk],   a0e);
          a1e = MFMA16(hf[kk],   *(const bf16x8*)&wlds[kk*32],     a1e);
          a0o = MFMA16(hf[kk+1], bw[kk+1], a0o);
          a1o = MFMA16(hf[kk+1], *(const bf16x8*)&wlds[(kk+1)*32], a1o);
        }
        asm volatile("s_waitcnt vmcnt(0)"
          : "+v"(hf[16]),"+v"(hf[17]),"+v"(hf[18]),"+v"(hf[19]),
            "+v"(hf[20]),"+v"(hf[21]),"+v"(hf[22]),"+v"(hf[23]),
            "+v"(xn0),"+v"(xn1) :: "memory");
        #pragma unroll
        for (int kk = 16; kk < 24; kk += 2) {
          a0e = MFMA16(hf[kk],   bw[kk],   a0e);
          a1e = MFMA16(hf[kk],   *(const bf16x8*)&wlds[kk*32],     a1e);
          a0o = MFMA16(hf[kk+1], bw[kk+1], a0o);
          a1o = MFMA16(hf[kk+1], *(const bf16x8*)&wlds[(kk+1)*32], a1o);
        }
        xf0 = xn0; xf1 = xn1;
        f32x4 A0 = a0e + a0o, A1 = a1e + a1o;
        // stage D
        {
          const int c0 = wave*32 + l16;
          #pragma unroll
          for (int r = 0; r < 4; r++) {
            const int rb = quad*4 + r;
            sGH2[s][rb][c0]    = A0[r];
            sGH2[s][rb][c0+16] = A1[r];
          }
          if (wave == 1) {
            #pragma unroll
            for (int r = 0; r < 4; r++) sGIN[s][quad*4 + r][l16] = gi[r];
          } else if (wave == 2) {
            #pragma unroll
            for (int r = 0; r < 4; r++) sGIN[s][quad*4 + r][16 + l16] = gi[r];
          }
        }
      }
    } else if (k > 0) {
      // ---- service wave: process phase k-1 ----
      const int pt = (k-1) >> 1, ps = (k-1) & 1;
      const int b = lane >> 2, jp = (lane & 3) * 6;
      const int bg = ps*16 + b;
      float hn[6];
      #pragma unroll
      for (int u = 0; u < 6; u += 2) {
        f32x2 gr  = *(const f32x2*)&sGH2[ps][b][jp+u];
        f32x2 gz  = *(const f32x2*)&sGH2[ps][b][24+jp+u];
        f32x2 gn  = *(const f32x2*)&sGH2[ps][b][48+jp+u];
        f32x2 gi2 = *(const f32x2*)&sGIN[ps][b][jp+u];
        f32x2 hm  = *(const f32x2*)&sHm[bg][jp+u];
        f32x2 bir = *(const f32x2*)&sBih[jp+u],    bhr = *(const f32x2*)&sBhh[jp+u];
        f32x2 biz = *(const f32x2*)&sBih[24+jp+u], bhz = *(const f32x2*)&sBhh[24+jp+u];
        f32x2 bin_= *(const f32x2*)&sBih[48+jp+u], bhn = *(const f32x2*)&sBhh[48+jp+u];
        #pragma unroll
        for (int v = 0; v < 2; v++) {
          float rr = sigmoidf_(gr[v] + bir[v] + bhr[v]);
          float zz = sigmoidf_(gz[v] + biz[v] + bhz[v]);
          float nn = tanhf_(gi2[v] + bin_[v] + rr*(gn[v] + bhn[v]));
          hn[u+v] = (1.f - zz)*nn + zz*hm[v];
        }
        f32x2 st; st[0] = hn[u]; st[1] = hn[u+1];
        *(f32x2*)&sHm[bg][jp+u] = st;
      }
      // publish (plain stores -> XCD L2)
      {
        unsigned* hb = (unsigned*)(g_hbuf + (size_t)((pt+1)&1)*B_N*H_N);
        const size_t eb = ((size_t)(g*32+bg)*H_N + j0 + jp) >> 1;
        #pragma unroll
        for (int u = 0; u < 3; u++) {
          union { bf16 h[2]; unsigned w; } pk;
          pk.h[0] = (bf16)hn[2*u]; pk.h[1] = (bf16)hn[2*u+1];
          hb[eb + u] = pk.w;
        }
      }
      asm volatile("s_waitcnt vmcnt(0)" ::: "memory");   // wave-local drain
      if (lane == 0)
        __hip_atomic_store(&g_flag[myflag + ps*32], (unsigned)(pt + 2),
                           __ATOMIC_RELAXED, __HIP_MEMORY_SCOPE_AGENT);
      // hidden verification poll -> token (hides next phase's poll latency)
      if (poll_flags(midx0 + (unsigned)(ps*32), (unsigned)(pt + 2))) {
        if (lane == 0) sTok[ps] = (unsigned)(pt + 2);
      }
      // deferred epilogue for tt = pt-1 (own set only)
      if (ps == s_own && lane < 16) {
        if (pt > 0) {
          const int tt = pt - 1;
          float wp = softplusf_(sGH2[ps][bqL][72+lane] + sWrb[lane]);
          float hl = hl_pf;
          if (tt == 0) { wp0_r = wp; hl0_r = hl; ct0_r = ct_pf; }
          else {
            size_t o = (size_t)bq*T_N + tt;
            float cv = hl*wp;
            hillZ[o*16 + lane] = wp;
            hill[o*16 + lane]  = cv;
            float cs = cv;
            cs += __shfl_xor(cs, 8, 64);
            cs += __shfl_xor(cs, 4, 64);
            cs += __shfl_xor(cs, 2, 64);
            cs += __shfl_xor(cs, 1, 64);
            if (lane == 0) outy[o] = cs + ct_pf + regt + bias0;
            if (tt == 1) {
              float w0 = 0.5f*(wp + wp0_r);
              float c0v = hl0_r*w0;
              size_t o0 = (size_t)bq*T_N;
              hillZ[o0*16 + lane] = w0;
              hill[o0*16 + lane]  = c0v;
              float cs0 = c0v;
              cs0 += __shfl_xor(cs0, 8, 64);
              cs0 += __shfl_xor(cs0, 4, 64);
              cs0 += __shfl_xor(cs0, 2, 64);
              cs0 += __shfl_xor(cs0, 1, 64);
              if (lane == 0) outy[o0] = cs0 + ct0_r + regt + bias0;
            }
          }
        }
        hl_pf = hill[((size_t)bq*T_N + pt)*16 + lane];
        if (lane == 0) ct_pf = g_ctrl[(size_t)bq*T_N + pt];
      }
    }
    __syncthreads();   // the ONLY barrier per phase
  }

  // ---- tail: head for tt = T-1 from h_T (own set; cold path) ----
  if (wave == 2) {
    poll_flags(midx0 + (unsigned)(s_own*32), (unsigned)(T_N + 1));
    const bf16* hsrc = g_hbuf + (size_t)((T_N)&1)*B_N*H_N
                     + (size_t)(g*32 + s_own*16 + l16)*H_N + quad*8;
    bf16x8 hf[24];
    HL(0,"0");    HL(1,"64");   HL(2,"128");  HL(3,"192");
    HL(4,"256");  HL(5,"320");  HL(6,"384");  HL(7,"448");
    HL(8,"512");  HL(9,"576");  HL(10,"640"); HL(11,"704");
    HL(12,"768"); HL(13,"832"); HL(14,"896"); HL(15,"960");
    HL(16,"1024");HL(17,"1088");HL(18,"1152");HL(19,"1216");
    HL(20,"1280");HL(21,"1344");HL(22,"1408");HL(23,"1472");
    asm volatile("s_waitcnt vmcnt(0)"
      : "+v"(hf[0]),"+v"(hf[1]),"+v"(hf[2]),"+v"(hf[3]),
        "+v"(hf[4]),"+v"(hf[5]),"+v"(hf[6]),"+v"(hf[7]) :: "memory");
    asm volatile(""
      : "+v"(hf[8]),"+v"(hf[9]),"+v"(hf[10]),"+v"(hf[11]),
        "+v"(hf[12]),"+v"(hf[13]),"+v"(hf[14]),"+v"(hf[15]));
    asm volatile(""
      : "+v"(hf[16]),"+v"(hf[17]),"+v"(hf[18]),"+v"(hf[19]),
        "+v"(hf[20]),"+v"(hf[21]),"+v"(hf[22]),"+v"(hf[23]));
    f32x4 az; az[0]=0.f; az[1]=0.f; az[2]=0.f; az[3]=0.f;
    f32x4 a0e=az, a0o=az, a1e=az, a1o=az;
    #pragma unroll
    for (int kk = 0; kk < 24; kk += 2) {
      a0e = MFMA16(hf[kk],   bw[kk],   a0e);
      a1e = MFMA16(hf[kk],   *(const bf16x8*)&wlds[kk*32],     a1e);
      a0o = MFMA16(hf[kk+1], bw[kk+1], a0o);
      a1o = MFMA16(hf[kk+1], *(const bf16x8*)&wlds[(kk+1)*32], a1o);
    }
    f32x4 A0 = a0e + a0o, A1 = a1e + a1o;
    #pragma unroll
    for (int r = 0; r < 4; r++) {
      const int rb = quad*4 + r;
      sGH2[0][rb][64 + l16] = A0[r];
      sGH2[0][rb][80 + l16] = A1[r];
    }
  }
  __syncthreads();
  if (tid < 16) {
    const int tt = T_N - 1;
    float wp = softplusf_(sGH2[0][bqL][72+tid] + sWrb[tid]);
    float hl = hill[((size_t)bq*T_N + tt)*16 + tid];
    size_t o = (size_t)bq*T_N + tt;
    float cv = hl*wp;
    hillZ[o*16 + tid] = wp;
    hill[o*16 + tid]  = cv;
    float cs = cv;
    cs += __shfl_xor(cs, 8, 64);
    cs += __shfl_xor(cs, 4, 64);
    cs += __shfl_xor(cs, 2, 64);
    cs += __shfl_xor(cs, 1, 64);
    if (tid == 0) outy[o] = cs + g_ctrl[o] + regt + bias0;
  }
}

extern "C" void kernel_launch(void* const* d_in, const int* in_sizes, int n_in,
                              void* d_out, int out_size, void* d_ws, size_t ws_size,
                              hipStream_t stream) {
  const float* Xm    = (const float*)d_in[0];
  const float* Xc    = (const float*)d_in[1];
  const float* Aw    = (const float*)d_in[3];
  const float* ew1   = (const float*)d_in[4];
  const float* eb1   = (const float*)d_in[5];
  const float* ew2   = (const float*)d_in[6];
  const float* eb2   = (const float*)d_in[7];
  const float* nw    = (const float*)d_in[8];
  const float* nb    = (const float*)d_in[9];
  const float* Wih   = (const float*)d_in[10];
  const float* Whh   = (const float*)d_in[11];
  const float* bih   = (const float*)d_in[12];
  const float* bhh   = (const float*)d_in[13];
  const float* wraww = (const float*)d_in[14];
  const float* wrawb = (const float*)d_in[15];
  const float* alpha = (const float*)d_in[16];
  const float* hilla = (const float*)d_in[17];
  const float* hillg = (const float*)d_in[18];
  const float* cw    = (const float*)d_in[19];
  const float* cb    = (const float*)d_in[20];
  const float* regemb= (const float*)d_in[21];
  const float* bias  = (const float*)d_in[22];
  const float* h0    = (const float*)d_in[23];

  float* outy = (float*)d_out;
  float* outw = outy + 256*512;          // doubles as Z / hillZ scratch
  float* outc = outw + 256*512*16;       // doubles as hill scratch

  k_zero<<<1, 256, 0, stream>>>();
  k_encode<<<512, 256, 0, stream>>>(Xm, Xc, Aw, ew1, eb1, ew2, eb2, nw, nb, cw, cb,
                                    outw);
  k_adstock<<<64, 64, 0, stream>>>(Xm, alpha, hilla, hillg, outw, outc);
  // Plain launch: grid==256 CUs + ~96KB LDS (1 blk/CU) => all blocks co-resident.
  k_gru<<<dim3(256), dim3(256), 0, stream>>>(
      Xc, Wih, Whh, bih, bhh, wraww, wrawb, regemb, bias, h0,
      outw, outc, outy);
}

// Round 5
// 3783.281 us; speedup vs baseline: 1.1331x; 1.1331x over previous
//
#include <hip/hip_runtime.h>

typedef __bf16 bf16;
typedef bf16 bf16x8 __attribute__((ext_vector_type(8)));
typedef bf16 bf16x4 __attribute__((ext_vector_type(4)));
typedef float f32x4 __attribute__((ext_vector_type(4)));
typedef float f32x2 __attribute__((ext_vector_type(2)));

#define MFMA16(a,b,c) __builtin_amdgcn_mfma_f32_16x16x32_bf16((a),(b),(c),0,0,0)

#define B_N 256
#define T_N 512
#define H_N 768

// ---- device-global scratch (BSS) ----
__device__ float    g_ctrl[B_N * T_N];          // 512 KB
__device__ bf16     g_hbuf[2 * B_N * H_N];      // 768 KB (bf16 h exchange, intra-XCD L2)
__device__ unsigned g_flag[256 * 64];           // per-(block,set) flag, 128B apart
__device__ unsigned g_members[8 * 32];          // XCD roster -> blockIdx table
__device__ unsigned g_roster[8];
__device__ unsigned g_sync;

__device__ __forceinline__ float sigmoidf_(float x){ return 1.f/(1.f+__expf(-x)); }
__device__ __forceinline__ float tanhf_(float x){
  float e = __expf(-2.f*fabsf(x));
  float t = (1.f-e)/(1.f+e);
  return copysignf(t, x);
}
__device__ __forceinline__ float softplusf_(float x){
  return x > 20.f ? x : log1pf(__expf(x));
}
__device__ __forceinline__ bf16x8 ld_bf8(const float* p){
  f32x4 a = *(const f32x4*)p;
  f32x4 b = *(const f32x4*)(p + 4);
  bf16x8 v;
  v[0]=(bf16)a[0]; v[1]=(bf16)a[1]; v[2]=(bf16)a[2]; v[3]=(bf16)a[3];
  v[4]=(bf16)b[0]; v[5]=(bf16)b[1]; v[6]=(bf16)b[2]; v[7]=(bf16)b[3];
  return v;
}

__global__ void k_zero() {
  const int tid = threadIdx.x;
  for (int i = tid; i < 256*64; i += 256) g_flag[i] = 0u;
  if (tid < 256) g_members[tid] = 0u;   // fallback: block 0's flags (always advance)
  if (tid < 8)   g_roster[tid] = 0u;
  if (tid == 0)  g_sync = 0u;
}

// ---------------- kernel A: causal encoder Z + ctrl term (unchanged) ----------------
__global__ __launch_bounds__(256) void k_encode(
    const float* __restrict__ Xm, const float* __restrict__ Xc,
    const float* __restrict__ Aw,
    const float* __restrict__ ew1, const float* __restrict__ eb1,
    const float* __restrict__ ew2, const float* __restrict__ eb2,
    const float* __restrict__ nw,  const float* __restrict__ nb,
    const float* __restrict__ cw,  const float* __restrict__ cb,
    float* __restrict__ Zout)
{
  __shared__ float sA[16][16], sE1[16][32], sE2[16][16], sNW[16][32];
  __shared__ float sEB1[16], sEB2[16], sNB[16];
  __shared__ float sCW[768][16];
  __shared__ float sCB[768];
  const int tid = threadIdx.x;
  for (int i = tid; i < 256; i += 256) sA[i>>4][i&15] = Aw[i];
  for (int i = tid; i < 512; i += 256) sE1[i>>5][i&31] = ew1[i];
  for (int i = tid; i < 256; i += 256) sE2[i>>4][i&15] = ew2[i];
  for (int i = tid; i < 512; i += 256) sNW[i>>5][i&31] = nw[i];
  if (tid < 16) { sEB1[tid]=eb1[tid]; sEB2[tid]=eb2[tid]; sNB[tid]=nb[tid]; }
  for (int i = tid; i < 768*16; i += 256) sCW[i>>4][i&15] = cw[i];
  for (int i = tid; i < 768; i += 256) sCB[i] = cb[i];
  __syncthreads();
  const int idx = blockIdx.x*256 + tid;           // flat (b*T + t)
  const float* xmp = Xm + (size_t)idx*16;
  const float* xcp = Xc + (size_t)idx*16;
  float xm[16], xc[16];
  #pragma unroll
  for (int j=0;j<4;j++){
    *(f32x4*)&xm[j*4] = *(const f32x4*)(xmp + j*4);
    *(f32x4*)&xc[j*4] = *(const f32x4*)(xcp + j*4);
  }
  float snd[16], rcv[16];
  #pragma unroll
  for (int i=0;i<16;i++){
    float s=0.f, r=0.f;
    #pragma unroll
    for (int j=0;j<16;j++){ s += xm[j]*sA[i][j]; r += xm[j]*sA[j][i]; }
    snd[i]=s; rcv[i]=r;
  }
  float he[16];
  #pragma unroll
  for (int i=0;i<16;i++){
    float a = sEB1[i];
    #pragma unroll
    for (int k=0;k<16;k++) a += snd[k]*sE1[i][k];
    #pragma unroll
    for (int k=0;k<16;k++) a += rcv[k]*sE1[i][16+k];
    he[i] = fmaxf(a, 0.f);
  }
  float he2[16];
  #pragma unroll
  for (int i=0;i<16;i++){
    float a = sEB2[i];
    #pragma unroll
    for (int k=0;k<16;k++) a += he[k]*sE2[i][k];
    he2[i] = fmaxf(a, 0.f);
  }
  float* zp = Zout + (size_t)idx*16;
  #pragma unroll
  for (int m=0;m<16;m++){
    float a = sNB[m];
    #pragma unroll
    for (int k=0;k<16;k++) a += xm[k]*sNW[m][k];
    #pragma unroll
    for (int k=0;k<16;k++) a += he2[k]*sNW[m][16+k];
    zp[m] = fmaxf(a, 0.f);
  }
  float cs = 0.f;
  for (int i=0;i<768;i++){
    float a = sCB[i];
    #pragma unroll
    for (int k=0;k<16;k++) a += xc[k]*sCW[i][k];
    cs += fmaxf(a, 0.f);
  }
  g_ctrl[idx] = cs * 0.3f;
}

// ---------------- kernel B: adstock scan + hill + gru-input (unchanged) ----------------
__global__ __launch_bounds__(64) void k_adstock(
    const float* __restrict__ Xm, const float* __restrict__ alpha,
    const float* __restrict__ hill_a, const float* __restrict__ hill_g,
    float* __restrict__ Zio, float* __restrict__ hill_out)
{
  const int gid = blockIdx.x*64 + threadIdx.x;   // (b, m)
  const int b = gid >> 4, m = gid & 15;
  float a  = fminf(fmaxf(alpha[m],  0.f),  1.f);
  float ha = fminf(fmaxf(hill_a[m], 0.1f), 3.f);
  float hg = fminf(fmaxf(hill_g[m], 0.1f), 2.f);
  float gpow = __powf(hg, ha);
  const float* xp = Xm + (size_t)b*T_N*16 + m;
  float prev = 0.f, cmax = 0.f;
  for (int t=0;t<T_N;t++){ float x = xp[(size_t)t*16]; prev = x + a*prev; cmax = fmaxf(cmax, prev); }
  cmax = fmaxf(cmax, 1e-6f);
  float inv = 1.f/cmax;
  prev = 0.f;
  float* zp  = Zio      + (size_t)b*T_N*16 + m;
  float* hp  = hill_out + (size_t)b*T_N*16 + m;
  for (int t=0;t<T_N;t++){
    float x = xp[(size_t)t*16];
    prev = x + a*prev;
    float xn  = fmaxf(prev*inv, 0.f);
    float num = __powf(xn, ha);
    float h   = num / (num + gpow + 1e-8f);
    float z   = zp[(size_t)t*16];
    hp[(size_t)t*16] = h;
    zp[(size_t)t*16] = h + z;
  }
}

// ---------------- kernel C: persistent GRU + fused heads ----------------
// r4 = r1's proven 2-phase structure with three fixes:
//  * B3 removed: gates on waves 1-3 only; per-wave vmcnt(0) drain + flag
//    fetch_add(+1); pollers wait for 3*(t+1). 2 barriers/slot.
//  * volley fragments kept in regs: each wave's 6 loads ARE its A-fragments
//    for kt=6w..6w+5 -> 18 of 36 MFMAs run BEFORE B1; only 6 partner kts
//    re-read from LDS.
//  * sW2 XOR-swizzled ((row&7)<<3, involution applied on write and read);
//    input-fold mapping corrected (T0,T1,T2 folded; T3,T4 n-inputs -> sGIN).
// Tiles of 16 rows (local rows 0..23 r | 24..47 z | 48..71 n | 72..87 head):
//   wave w (rg=w&1, kh=w>>1): regs bw0=(rg?T3:T0), bw1=(rg?T4:T1);
//   LDS tile rg?T5:T2; K-half kt in [kh*12, kh*12+12).
__device__ __forceinline__ bool poll_flags(unsigned midx, unsigned val) {
  int tries = 0; bool ok = true;
  for (;;) {
    unsigned v = __hip_atomic_load(&g_flag[midx], __ATOMIC_RELAXED, __HIP_MEMORY_SCOPE_AGENT);
    if (__ballot(v >= val) == ~0ull) break;
    if (++tries > (1<<18)) { ok = false; break; }   // fail-visible, never hang
    if (tries > 8) __builtin_amdgcn_s_sleep(1);
  }
  __builtin_amdgcn_fence(__ATOMIC_ACQUIRE, "workgroup");
  return ok;
}

#define HLV(i, OFF) asm volatile("global_load_dwordx4 %0, %1, off offset:" OFF " sc0" \
      : "=v"(hv[i]) : "v"(hsrc) : "memory")

__global__ __launch_bounds__(256, 1) void k_gru(
    const float* __restrict__ Xc,
    const float* __restrict__ Wih, const float* __restrict__ Whh,
    const float* __restrict__ bih, const float* __restrict__ bhh,
    const float* __restrict__ wraww, const float* __restrict__ wrawb,
    const float* __restrict__ regemb, const float* __restrict__ bias,
    const float* __restrict__ h0,
    float* __restrict__ hillZ,       // = outw region (read until step t, then w_pos)
    float* __restrict__ hill,        // = outc region (read hill, overwrite contrib)
    float* __restrict__ outy)
{
  __shared__ __align__(16) bf16 sW2[32*768];      // 49,152 B : tiles T2,T5 (swizzled)
  __shared__ __align__(16) bf16 sH[16*768];       // 24,576 B : active-set h (swizzled)
  __shared__ __align__(16) float sGH2[2][16][100];// 12,800 B : D partials per kh
  __shared__ __align__(16) float sGIN[16][32];    //  2,048 B : n-gate input part
  __shared__ __align__(16) float sHm[32][28];     //  3,584 B : f32 master h (both sets)
  __shared__ __align__(16) float sBih[72], sBhh[72]; // 576 B
  __shared__ float sWrb[16];
  __shared__ float sScal[2];
  __shared__ unsigned sGP[2];

  const int tid = threadIdx.x;
  const int wave = tid >> 6, lane = tid & 63;
  const int quad = lane >> 4, l16 = lane & 15;
  const int rg = wave & 1, kh = wave >> 1;

  // runtime group discovery: g = physical XCD
  if (tid == 0) {
    unsigned x;
    asm volatile("s_getreg_b32 %0, hwreg(HW_REG_XCC_ID, 0, 32)" : "=s"(x));
    x &= 7u;
    unsigned slot = __hip_atomic_fetch_add(&g_roster[x], 1u,
                        __ATOMIC_RELAXED, __HIP_MEMORY_SCOPE_AGENT);
    if (slot < 32u)
      __hip_atomic_store(&g_members[x*32u + slot], (unsigned)blockIdx.x,
                         __ATOMIC_RELAXED, __HIP_MEMORY_SCOPE_AGENT);
    sGP[0] = x; sGP[1] = slot & 31u;
    __hip_atomic_fetch_add(&g_sync, 1u, __ATOMIC_RELEASE, __HIP_MEMORY_SCOPE_AGENT);
    int tries = 0;
    while (__hip_atomic_load(&g_sync, __ATOMIC_ACQUIRE, __HIP_MEMORY_SCOPE_AGENT) < 256u) {
      if (++tries > (1<<20)) break;
      __builtin_amdgcn_s_sleep(1);
    }
  }
  __syncthreads();
  const int g = (int)sGP[0], p = (int)sGP[1];
  const int j0 = p*24;
  const int s_own = (p >= 16) ? 1 : 0;
  const int bqL = p & 15;
  const int bq = g*32 + p;
  const unsigned member = __hip_atomic_load(&g_members[g*32 + (lane & 31)],
                              __ATOMIC_RELAXED, __HIP_MEMORY_SCOPE_AGENT);
  const unsigned midx0 = member * 64u;
  const unsigned myflag = (unsigned)blockIdx.x * 64u;

  // ---- stage LDS weight tiles T2 (rl<16 -> L=32+rl) / T5 (rl>=16 -> L=64+rl),
  //      XOR-swizzled by (rl&7)<<3 on 8-elem granules
  for (int c = tid; c < 32*96; c += 256) {
    int rl = c / 96, jq = c - rl*96;
    int L = (rl < 16) ? (32 + rl) : (64 + rl);
    bf16x8 v;
    if (L < 72) {
      v = ld_bf8(&Whh[(size_t)((L/24)*768 + j0 + (L%24))*768 + jq*8]);
    } else if (L < 88) {
      v = ld_bf8(&wraww[(size_t)(L-72)*768 + jq*8]);
    } else {
      for (int i=0;i<8;i++) v[i]=(bf16)0.f;
    }
    *(bf16x8*)&sW2[rl*768 + ((jq*8) ^ ((rl&7)<<3))] = v;
  }
  if (tid < 72) {
    int grow = (tid/24)*768 + j0 + (tid%24);
    sBih[tid] = bih[grow];
    sBhh[tid] = bhh[grow];
  }
  if (tid >= 128 && tid < 144) sWrb[tid-128] = wrawb[tid-128];
  if (wave == 0) {
    float sacc = 0.f;
    for (int k = lane; k < 768; k += 64) sacc += regemb[k];  // reg_emb[0]
    #pragma unroll
    for (int off = 32; off; off >>= 1) sacc += __shfl_xor(sacc, off, 64);
    if (lane == 0) { sScal[0] = 0.3f*sacc; sScal[1] = bias[0]; }
  }

  // ---- per-wave t-invariant register weights ----
  bf16x8 bw0[12], bw1[12];
  {
    const int LA = (rg ? 48 : 0) + l16;               // < 72 always
    const int LB = (rg ? 64 : 16) + l16;              // rg1,l16>=8 -> head rows 72..79
    const float* rowA = Whh + (size_t)((LA/24)*768 + j0 + (LA%24))*768;
    const float* rowB = (LB < 72)
        ? (Whh + (size_t)((LB/24)*768 + j0 + (LB%24))*768)
        : (wraww + (size_t)(LB-72)*768);
    #pragma unroll
    for (int kk = 0; kk < 12; kk++) {
      const int col = (kh*12 + kk)*32 + quad*8;
      bw0[kk] = ld_bf8(rowA + col);
      bw1[kk] = ld_bf8(rowB + col);
    }
  }
  // input weights: wave0 folds T0,T1,T2; wave1 computes T3,T4 n-inputs (sGIN)
  bf16x8 wfA, wfB, wfC;
  #pragma unroll
  for (int i = 0; i < 8; i++) { wfA[i]=(bf16)0.f; wfB[i]=(bf16)0.f; wfC[i]=(bf16)0.f; }
  if (wave == 0) {
    { const int L = l16;      wfA = ld_bf8(Wih + (size_t)((L/24)*768 + j0 + (L%24))*32 + quad*8); }
    { const int L = 16 + l16; wfB = ld_bf8(Wih + (size_t)((L/24)*768 + j0 + (L%24))*32 + quad*8); }
    { const int L = 32 + l16; wfC = ld_bf8(Wih + (size_t)((L/24)*768 + j0 + (L%24))*32 + quad*8); }
  } else if (wave == 1) {
    { const int L = 48 + l16; wfA = ld_bf8(Wih + (size_t)((L/24)*768 + j0 + (L%24))*32 + quad*8); }
    { const int L = 64 + l16;
      if (L < 72) wfB = ld_bf8(Wih + (size_t)((L/24)*768 + j0 + (L%24))*32 + quad*8); }
  }

  // ---- init h (parity 0): f32 master + bf16 publish ----
  {
    unsigned* hb = (unsigned*)g_hbuf;
    for (int e = tid; e < 384; e += 256) {
      int b = e/12, j = (e - b*12)*2;
      float f0 = h0[j0+j], f1 = h0[j0+j+1];
      sHm[b][j] = f0; sHm[b][j+1] = f1;
      union { bf16 h[2]; unsigned u; } pk;
      pk.h[0] = (bf16)f0; pk.h[1] = (bf16)f1;
      hb[((size_t)(g*32+b)*H_N + j0 + j) >> 1] = pk.u;
    }
  }
  __syncthreads();   // drains init publishes (vmcnt(0)) + LDS staging
  if (tid == 0) {
    __hip_atomic_store(&g_flag[myflag],      3u, __ATOMIC_RELAXED, __HIP_MEMORY_SCOPE_AGENT);
    __hip_atomic_store(&g_flag[myflag + 32], 3u, __ATOMIC_RELAXED, __HIP_MEMORY_SCOPE_AGENT);
  }
  const float regt = sScal[0], bias0 = sScal[1];

  // wave0 epilogue state
  float wp0_r = 0.f, hl0_r = 0.f, ct0_r = 0.f;
  float hl_pf = 0.f, ct_pf = 0.f;
  if (wave == 0 && lane < 16) {
    hl_pf = hill[(size_t)bq*T_N*16 + lane];
    if (lane == 0) ct_pf = g_ctrl[(size_t)bq*T_N];
  }

  // x prologue for phase (t=0,s=0): kh0 waves only
  f32x4 xf0, xf1;
  xf0[0]=0.f; xf0[1]=0.f; xf0[2]=0.f; xf0[3]=0.f; xf1 = xf0;
  if (kh == 0) {
    const int gb0 = g*32 + l16;
    const float* srcx = (quad < 2)
        ? hillZ + (size_t)gb0*T_N*16 + quad*8
        : Xc    + (size_t)gb0*T_N*16 + (quad-2)*8;
    xf0 = *(const f32x4*)srcx;
    xf1 = *(const f32x4*)(srcx + 4);
  }
  const int swz = (l16 & 7) << 3;
  const int wrow = (rg*16 + l16)*768;     // base elem of this wave's LDS weight row
  const int hrow = l16*768;               // base elem of this lane's sH row

  #pragma unroll 1
  for (int k = 0; k < 2*T_N; k++) {
    const int t = k >> 1, s = k & 1;
    // ---- poll: all members published h_t of this set ----
    poll_flags(midx0 + (unsigned)(s*32), 3u*(unsigned)(t + 1));
    // ---- volley: 6 own A-fragments (kt = 6*wave + j), sc0 direct-L2 ----
    const bf16* hsrc = g_hbuf + (size_t)(t&1)*B_N*H_N
                     + (size_t)(g*32 + s*16 + l16)*H_N + wave*192 + quad*8;
    bf16x8 hv[6];
    HLV(0,"0"); HLV(1,"64"); HLV(2,"128"); HLV(3,"192"); HLV(4,"256"); HLV(5,"320");
    // x loads for NEXT phase (issued after hv so counted vmcnt works)
    f32x4 xn0, xn1;
    if (kh == 0) {
      const int sn = s ^ 1;
      int tn = s ? (t + 1) : t; if (tn >= T_N) tn = T_N - 1;
      const int gbn = g*32 + sn*16 + l16;
      const float* srcx = (quad < 2)
          ? hillZ + ((size_t)gbn*T_N + tn)*16 + quad*8
          : Xc    + ((size_t)gbn*T_N + tn)*16 + (quad-2)*8;
      asm volatile("global_load_dwordx4 %0, %2, off\n\t"
                   "global_load_dwordx4 %1, %2, off offset:16"
                   : "=v"(xn0), "=v"(xn1) : "v"(srcx) : "memory");
    }
    // input MFMAs from last phase's x (independent of the volley)
    f32x4 az; az[0]=0.f; az[1]=0.f; az[2]=0.f; az[3]=0.f;
    f32x4 a0e=az, a0o=az, a1e=az, a1o=az, a2e=az, a2o=az, gi0=az, gi1=az;
    {
      bf16x8 ax;
      ax[0]=(bf16)xf0[0]; ax[1]=(bf16)xf0[1]; ax[2]=(bf16)xf0[2]; ax[3]=(bf16)xf0[3];
      ax[4]=(bf16)xf1[0]; ax[5]=(bf16)xf1[1]; ax[6]=(bf16)xf1[2]; ax[7]=(bf16)xf1[3];
      if (wave == 0) {
        a0e = MFMA16(ax, wfA, a0e);      // T0 fold
        a1e = MFMA16(ax, wfB, a1e);      // T1 fold
        a2e = MFMA16(ax, wfC, a2e);      // T2 fold
      } else if (wave == 1) {
        gi0 = MFMA16(ax, wfA, gi0);      // T3 n-input
        gi1 = MFMA16(ax, wfB, gi1);      // T4 n-input (head rows zero)
      }
    }
    // ---- wait own fragments (x loads may stay in flight for kh0) ----
    if (kh == 0) {
      asm volatile("s_waitcnt vmcnt(2)"
        : "+v"(hv[0]),"+v"(hv[1]),"+v"(hv[2]),"+v"(hv[3]),"+v"(hv[4]),"+v"(hv[5])
        :: "memory");
    } else {
      asm volatile("s_waitcnt vmcnt(0)"
        : "+v"(hv[0]),"+v"(hv[1]),"+v"(hv[2]),"+v"(hv[3]),"+v"(hv[4]),"+v"(hv[5])
        :: "memory");
    }
    // publish own fragments to sH (swizzled) + own-kt MFMAs (pre-barrier)
    {
      bf16* hdst = &sH[hrow];
      #pragma unroll
      for (int j = 0; j < 6; j++)
        *(bf16x8*)&hdst[(((wave*6 + j)*32) + quad*8) ^ swz] = hv[j];
    }
    #pragma unroll
    for (int j = 0; j < 6; j += 2) {
      const int i0 = kh*6 + j;
      const int kt0 = wave*6 + j;
      a0e = MFMA16(hv[j],   bw0[i0],   a0e);
      a1e = MFMA16(hv[j],   bw1[i0],   a1e);
      a2e = MFMA16(hv[j],   *(const bf16x8*)&sW2[wrow + ((kt0*32 + quad*8) ^ swz)], a2e);
      a0o = MFMA16(hv[j+1], bw0[i0+1], a0o);
      a1o = MFMA16(hv[j+1], bw1[i0+1], a1o);
      a2o = MFMA16(hv[j+1], *(const bf16x8*)&sW2[wrow + (((kt0+1)*32 + quad*8) ^ swz)], a2o);
    }
    __syncthreads();   // B1: all volleys in sH
    // partner-kt MFMAs (A from sH): the OTHER wave with same kh owns kt=6*(wave^1)..
    #pragma unroll
    for (int j = 0; j < 6; j += 2) {
      const int i0 = (1 - kh)*0 + ((wave^1)>>1 == kh ? 0 : 0); // placeholder, fixed below
      (void)i0;
      const int kt0 = (wave ^ 1)*6 + j;
      const int iw = ((wave ^ 1) >> 1)*6 + j;   // index into this wave's 12-deep bw arrays
      bf16x8 p0 = *(const bf16x8*)&sH[hrow + ((kt0*32 + quad*8) ^ swz)];
      bf16x8 p1 = *(const bf16x8*)&sH[hrow + (((kt0+1)*32 + quad*8) ^ swz)];
      a0e = MFMA16(p0, bw0[iw],   a0e);
      a1e = MFMA16(p0, bw1[iw],   a1e);
      a2e = MFMA16(p0, *(const bf16x8*)&sW2[wrow + ((kt0*32 + quad*8) ^ swz)], a2e);
      a0o = MFMA16(p1, bw0[iw+1], a0o);
      a1o = MFMA16(p1, bw1[iw+1], a1o);
      a2o = MFMA16(p1, *(const bf16x8*)&sW2[wrow + (((kt0+1)*32 + quad*8) ^ swz)], a2o);
    }
    // retire next-x loads into the rotating regs
    if (kh == 0) {
      asm volatile("s_waitcnt vmcnt(0)" : "+v"(xn0), "+v"(xn1) :: "memory");
      xf0 = xn0; xf1 = xn1;
    }
    // ---- stage D (per-kh partials) ----
    {
      f32x4 A0 = a0e + a0o, A1 = a1e + a1o, A2 = a2e + a2o;
      const int c0 = rg*48 + l16;
      #pragma unroll
      for (int r = 0; r < 4; r++) {
        const int rb = quad*4 + r;
        sGH2[kh][rb][c0]      = A0[r];
        sGH2[kh][rb][c0+16]   = A1[r];
        sGH2[kh][rb][c0+32]   = A2[r];
      }
      if (wave == 1) {
        #pragma unroll
        for (int r = 0; r < 4; r++) {
          const int rb = quad*4 + r;
          sGIN[rb][l16]      = gi0[r];
          sGIN[rb][16 + l16] = gi1[r];
        }
      }
    }
    __syncthreads();   // B2: D complete
    if (wave != 0) {
      // ---- gates on waves 1-3: one (b, jp) dim-pair per thread ----
      const int idxg = (wave - 1)*64 + lane;     // 0..191
      const int b = idxg / 12;
      const int jp = (idxg - b*12)*2;
      const int bg = s*16 + b;
      f32x2 gr = *(const f32x2*)&sGH2[0][b][jp];
      { f32x2 q = *(const f32x2*)&sGH2[1][b][jp];       gr += q; }
      f32x2 gz = *(const f32x2*)&sGH2[0][b][24+jp];
      { f32x2 q = *(const f32x2*)&sGH2[1][b][24+jp];    gz += q; }
      f32x2 gn = *(const f32x2*)&sGH2[0][b][48+jp];
      { f32x2 q = *(const f32x2*)&sGH2[1][b][48+jp];    gn += q; }
      f32x2 gi2 = *(const f32x2*)&sGIN[b][jp];
      f32x2 hm  = *(const f32x2*)&sHm[bg][jp];
      f32x2 bir = *(const f32x2*)&sBih[jp],    bhr = *(const f32x2*)&sBhh[jp];
      f32x2 biz = *(const f32x2*)&sBih[24+jp], bhz = *(const f32x2*)&sBhh[24+jp];
      f32x2 bin_= *(const f32x2*)&sBih[48+jp], bhn = *(const f32x2*)&sBhh[48+jp];
      float hn[2];
      #pragma unroll
      for (int v = 0; v < 2; v++) {
        float rr = sigmoidf_(gr[v] + bir[v] + bhr[v]);
        float zz = sigmoidf_(gz[v] + biz[v] + bhz[v]);
        float nn = tanhf_(gi2[v] + bin_[v] + rr*(gn[v] + bhn[v]));
        hn[v] = (1.f - zz)*nn + zz*hm[v];
      }
      f32x2 st; st[0] = hn[0]; st[1] = hn[1];
      *(f32x2*)&sHm[bg][jp] = st;
      {
        unsigned* hb = (unsigned*)(g_hbuf + (size_t)((t+1)&1)*B_N*H_N);
        union { bf16 h[2]; unsigned w; } pk;
        pk.h[0] = (bf16)hn[0]; pk.h[1] = (bf16)hn[1];
        hb[((size_t)(g*32+bg)*H_N + j0 + jp) >> 1] = pk.w;
      }
      asm volatile("s_waitcnt vmcnt(0)" ::: "memory");   // wave-local drain
      if (lane == 0)
        __hip_atomic_fetch_add(&g_flag[myflag + s*32], 1u,
                               __ATOMIC_RELAXED, __HIP_MEMORY_SCOPE_AGENT);
    } else if (s == s_own) {
      // ---- wave0: heads/epilogue for tt = t-1 (overlaps gate drain) ----
      if (t > 0 && lane < 16) {
        const int tt = t - 1;
        float hd = sGH2[0][bqL][72+lane] + sGH2[1][bqL][72+lane];
        float wp = softplusf_(hd + sWrb[lane]);
        float hl = hl_pf;
        if (tt == 0) { wp0_r = wp; hl0_r = hl; ct0_r = ct_pf; }
        else {
          size_t o = (size_t)bq*T_N + tt;
          float cv = hl*wp;
          hillZ[o*16 + lane] = wp;
          hill[o*16 + lane]  = cv;
          float cs = cv;
          cs += __shfl_xor(cs, 8, 64);
          cs += __shfl_xor(cs, 4, 64);
          cs += __shfl_xor(cs, 2, 64);
          cs += __shfl_xor(cs, 1, 64);
          if (lane == 0) outy[o] = cs + ct_pf + regt + bias0;
          if (tt == 1) {
            float w0 = 0.5f*(wp + wp0_r);
            float c0v = hl0_r*w0;
            size_t o0 = (size_t)bq*T_N;
            hillZ[o0*16 + lane] = w0;
            hill[o0*16 + lane]  = c0v;
            float cs0 = c0v;
            cs0 += __shfl_xor(cs0, 8, 64);
            cs0 += __shfl_xor(cs0, 4, 64);
            cs0 += __shfl_xor(cs0, 2, 64);
            cs0 += __shfl_xor(cs0, 1, 64);
            if (lane == 0) outy[o0] = cs0 + ct0_r + regt + bias0;
          }
        }
      }
      if (lane < 16) {
        hl_pf = hill[((size_t)bq*T_N + t)*16 + lane];
        if (lane == 0) ct_pf = g_ctrl[(size_t)bq*T_N + t];
      }
    }
  }

  // ---- tail: head for tt = T-1 from h_T (own set; cold path) ----
  {
    poll_flags(midx0 + (unsigned)(s_own*32), 3u*(unsigned)(T_N + 1));
    const bf16* hsrc = g_hbuf + (size_t)(T_N & 1)*B_N*H_N
                     + (size_t)(g*32 + s_own*16 + l16)*H_N + wave*192 + quad*8;
    bf16x8 hv[6];
    HLV(0,"0"); HLV(1,"64"); HLV(2,"128"); HLV(3,"192"); HLV(4,"256"); HLV(5,"320");
    asm volatile("s_waitcnt vmcnt(0)"
      : "+v"(hv[0]),"+v"(hv[1]),"+v"(hv[2]),"+v"(hv[3]),"+v"(hv[4]),"+v"(hv[5])
      :: "memory");
    {
      bf16* hdst = &sH[hrow];
      #pragma unroll
      for (int j = 0; j < 6; j++)
        *(bf16x8*)&hdst[(((wave*6 + j)*32) + quad*8) ^ swz] = hv[j];
    }
  }
  __syncthreads();
  if (rg == 1) {
    f32x4 az; az[0]=0.f; az[1]=0.f; az[2]=0.f; az[3]=0.f;
    f32x4 a1e=az, a1o=az, a2e=az, a2o=az;
    #pragma unroll
    for (int kk = 0; kk < 12; kk += 2) {
      const int kt0 = kh*12 + kk;
      bf16x8 p0 = *(const bf16x8*)&sH[hrow + ((kt0*32 + quad*8) ^ swz)];
      bf16x8 p1 = *(const bf16x8*)&sH[hrow + (((kt0+1)*32 + quad*8) ^ swz)];
      a1e = MFMA16(p0, bw1[kk],   a1e);
      a2e = MFMA16(p0, *(const bf16x8*)&sW2[wrow + ((kt0*32 + quad*8) ^ swz)], a2e);
      a1o = MFMA16(p1, bw1[kk+1], a1o);
      a2o = MFMA16(p1, *(const bf16x8*)&sW2[wrow + (((kt0+1)*32 + quad*8) ^ swz)], a2o);
    }
    f32x4 A1 = a1e + a1o, A2 = a2e + a2o;
    #pragma unroll
    for (int r = 0; r < 4; r++) {
      const int rb = quad*4 + r;
      sGH2[kh][rb][64 + l16] = A1[r];
      sGH2[kh][rb][80 + l16] = A2[r];
    }
  }
  __syncthreads();
  if (tid < 16) {
    const int tt = T_N - 1;
    float hd = sGH2[0][bqL][72+tid] + sGH2[1][bqL][72+tid];
    float wp = softplusf_(hd + sWrb[tid]);
    float hl = hill[((size_t)bq*T_N + tt)*16 + tid];
    size_t o = (size_t)bq*T_N + tt;
    float cv = hl*wp;
    hillZ[o*16 + tid] = wp;
    hill[o*16 + tid]  = cv;
    float cs = cv;
    cs += __shfl_xor(cs, 8, 64);
    cs += __shfl_xor(cs, 4, 64);
    cs += __shfl_xor(cs, 2, 64);
    cs += __shfl_xor(cs, 1, 64);
    if (tid == 0) outy[o] = cs + g_ctrl[o] + regt + bias0;
  }
}

extern "C" void kernel_launch(void* const* d_in, const int* in_sizes, int n_in,
                              void* d_out, int out_size, void* d_ws, size_t ws_size,
                              hipStream_t stream) {
  const float* Xm    = (const float*)d_in[0];
  const float* Xc    = (const float*)d_in[1];
  const float* Aw    = (const float*)d_in[3];
  const float* ew1   = (const float*)d_in[4];
  const float* eb1   = (const float*)d_in[5];
  const float* ew2   = (const float*)d_in[6];
  const float* eb2   = (const float*)d_in[7];
  const float* nw    = (const float*)d_in[8];
  const float* nb    = (const float*)d_in[9];
  const float* Wih   = (const float*)d_in[10];
  const float* Whh   = (const float*)d_in[11];
  const float* bih   = (const float*)d_in[12];
  const float* bhh   = (const float*)d_in[13];
  const float* wraww = (const float*)d_in[14];
  const float* wrawb = (const float*)d_in[15];
  const float* alpha = (const float*)d_in[16];
  const float* hilla = (const float*)d_in[17];
  const float* hillg = (const float*)d_in[18];
  const float* cw    = (const float*)d_in[19];
  const float* cb    = (const float*)d_in[20];
  const float* regemb= (const float*)d_in[21];
  const float* bias  = (const float*)d_in[22];
  const float* h0    = (const float*)d_in[23];

  float* outy = (float*)d_out;
  float* outw = outy + 256*512;          // doubles as Z / hillZ scratch
  float* outc = outw + 256*512*16;       // doubles as hill scratch

  k_zero<<<1, 256, 0, stream>>>();
  k_encode<<<512, 256, 0, stream>>>(Xm, Xc, Aw, ew1, eb1, ew2, eb2, nw, nb, cw, cb,
                                    outw);
  k_adstock<<<64, 64, 0, stream>>>(Xm, alpha, hilla, hillg, outw, outc);
  // Plain launch: grid==256 CUs + ~93KB LDS (1 blk/CU) => all blocks co-resident.
  k_gru<<<dim3(256), dim3(256), 0, stream>>>(
      Xc, Wih, Whh, bih, bhh, wraww, wrawb, regemb, bias, h0,
      outw, outc, outy);
}

// Round 7
// 3031.044 us; speedup vs baseline: 1.4143x; 1.2482x over previous
//
#include <hip/hip_runtime.h>

typedef __bf16 bf16;
typedef bf16 bf16x8 __attribute__((ext_vector_type(8)));
typedef bf16 bf16x4 __attribute__((ext_vector_type(4)));
typedef float f32x4 __attribute__((ext_vector_type(4)));

#define MFMA16(a,b,c) __builtin_amdgcn_mfma_f32_16x16x32_bf16((a),(b),(c),0,0,0)

#define B_N 256
#define T_N 512
#define H_N 768
#define WROW 776      // 768 + 8 pad (bf16 elems)

// ---- device-global scratch (BSS) ----
__device__ float    g_ctrl[B_N * T_N];          // 512 KB
__device__ bf16     g_hbuf[2 * B_N * H_N];      // 768 KB (bf16 h exchange, intra-XCD L2)
__device__ unsigned g_flag[256 * 64];           // per-(block,set) flag, 128B apart
__device__ unsigned g_members[8 * 32];          // XCD roster -> blockIdx table
__device__ unsigned g_roster[8];
__device__ unsigned g_sync;

__device__ __forceinline__ float sigmoidf_(float x){ return 1.f/(1.f+__expf(-x)); }
__device__ __forceinline__ float tanhf_(float x){
  float e = __expf(-2.f*fabsf(x));
  float t = (1.f-e)/(1.f+e);
  return copysignf(t, x);
}
__device__ __forceinline__ float softplusf_(float x){
  return x > 20.f ? x : log1pf(__expf(x));
}
__device__ __forceinline__ bf16x8 ld_bf8(const float* p){
  f32x4 a = *(const f32x4*)p;
  f32x4 b = *(const f32x4*)(p + 4);
  bf16x8 v;
  v[0]=(bf16)a[0]; v[1]=(bf16)a[1]; v[2]=(bf16)a[2]; v[3]=(bf16)a[3];
  v[4]=(bf16)b[0]; v[5]=(bf16)b[1]; v[6]=(bf16)b[2]; v[7]=(bf16)b[3];
  return v;
}

__global__ void k_zero() {
  const int tid = threadIdx.x;
  for (int i = tid; i < 256*64; i += 256) g_flag[i] = 0u;
  if (tid < 256) g_members[tid] = 0u;   // fallback: block 0's flags (always advance)
  if (tid < 8)   g_roster[tid] = 0u;
  if (tid == 0)  g_sync = 0u;
}

// ---------------- kernel A: causal encoder Z + ctrl term (unchanged) ----------------
__global__ __launch_bounds__(256) void k_encode(
    const float* __restrict__ Xm, const float* __restrict__ Xc,
    const float* __restrict__ Aw,
    const float* __restrict__ ew1, const float* __restrict__ eb1,
    const float* __restrict__ ew2, const float* __restrict__ eb2,
    const float* __restrict__ nw,  const float* __restrict__ nb,
    const float* __restrict__ cw,  const float* __restrict__ cb,
    float* __restrict__ Zout)
{
  __shared__ float sA[16][16], sE1[16][32], sE2[16][16], sNW[16][32];
  __shared__ float sEB1[16], sEB2[16], sNB[16];
  __shared__ float sCW[768][16];
  __shared__ float sCB[768];
  const int tid = threadIdx.x;
  for (int i = tid; i < 256; i += 256) sA[i>>4][i&15] = Aw[i];
  for (int i = tid; i < 512; i += 256) sE1[i>>5][i&31] = ew1[i];
  for (int i = tid; i < 256; i += 256) sE2[i>>4][i&15] = ew2[i];
  for (int i = tid; i < 512; i += 256) sNW[i>>5][i&31] = nw[i];
  if (tid < 16) { sEB1[tid]=eb1[tid]; sEB2[tid]=eb2[tid]; sNB[tid]=nb[tid]; }
  for (int i = tid; i < 768*16; i += 256) sCW[i>>4][i&15] = cw[i];
  for (int i = tid; i < 768; i += 256) sCB[i] = cb[i];
  __syncthreads();
  const int idx = blockIdx.x*256 + tid;           // flat (b*T + t)
  const float* xmp = Xm + (size_t)idx*16;
  const float* xcp = Xc + (size_t)idx*16;
  float xm[16], xc[16];
  #pragma unroll
  for (int j=0;j<4;j++){
    *(f32x4*)&xm[j*4] = *(const f32x4*)(xmp + j*4);
    *(f32x4*)&xc[j*4] = *(const f32x4*)(xcp + j*4);
  }
  float snd[16], rcv[16];
  #pragma unroll
  for (int i=0;i<16;i++){
    float s=0.f, r=0.f;
    #pragma unroll
    for (int j=0;j<16;j++){ s += xm[j]*sA[i][j]; r += xm[j]*sA[j][i]; }
    snd[i]=s; rcv[i]=r;
  }
  float he[16];
  #pragma unroll
  for (int i=0;i<16;i++){
    float a = sEB1[i];
    #pragma unroll
    for (int k=0;k<16;k++) a += snd[k]*sE1[i][k];
    #pragma unroll
    for (int k=0;k<16;k++) a += rcv[k]*sE1[i][16+k];
    he[i] = fmaxf(a, 0.f);
  }
  float he2[16];
  #pragma unroll
  for (int i=0;i<16;i++){
    float a = sEB2[i];
    #pragma unroll
    for (int k=0;k<16;k++) a += he[k]*sE2[i][k];
    he2[i] = fmaxf(a, 0.f);
  }
  float* zp = Zout + (size_t)idx*16;
  #pragma unroll
  for (int m=0;m<16;m++){
    float a = sNB[m];
    #pragma unroll
    for (int k=0;k<16;k++) a += xm[k]*sNW[m][k];
    #pragma unroll
    for (int k=0;k<16;k++) a += he2[k]*sNW[m][16+k];
    zp[m] = fmaxf(a, 0.f);
  }
  float cs = 0.f;
  for (int i=0;i<768;i++){
    float a = sCB[i];
    #pragma unroll
    for (int k=0;k<16;k++) a += xc[k]*sCW[i][k];
    cs += fmaxf(a, 0.f);
  }
  g_ctrl[idx] = cs * 0.3f;
}

// ---------------- kernel B: adstock scan + hill + gru-input (unchanged) ----------------
__global__ __launch_bounds__(64) void k_adstock(
    const float* __restrict__ Xm, const float* __restrict__ alpha,
    const float* __restrict__ hill_a, const float* __restrict__ hill_g,
    float* __restrict__ Zio, float* __restrict__ hill_out)
{
  const int gid = blockIdx.x*64 + threadIdx.x;   // (b, m)
  const int b = gid >> 4, m = gid & 15;
  float a  = fminf(fmaxf(alpha[m],  0.f),  1.f);
  float ha = fminf(fmaxf(hill_a[m], 0.1f), 3.f);
  float hg = fminf(fmaxf(hill_g[m], 0.1f), 2.f);
  float gpow = __powf(hg, ha);
  const float* xp = Xm + (size_t)b*T_N*16 + m;
  float prev = 0.f, cmax = 0.f;
  for (int t=0;t<T_N;t++){ float x = xp[(size_t)t*16]; prev = x + a*prev; cmax = fmaxf(cmax, prev); }
  cmax = fmaxf(cmax, 1e-6f);
  float inv = 1.f/cmax;
  prev = 0.f;
  float* zp  = Zio      + (size_t)b*T_N*16 + m;
  float* hp  = hill_out + (size_t)b*T_N*16 + m;
  for (int t=0;t<T_N;t++){
    float x = xp[(size_t)t*16];
    prev = x + a*prev;
    float xn  = fmaxf(prev*inv, 0.f);
    float num = __powf(xn, ha);
    float h   = num / (num + gpow + 1e-8f);
    float z   = zp[(size_t)t*16];
    hp[(size_t)t*16] = h;
    zp[(size_t)t*16] = h + z;
  }
}

// ---------------- kernel C: persistent GRU + fused heads ----------------
// r7 = the PROVEN r1 kernel (2610us, passed) + ONE change: the poll + h-volley
// ISSUE for phase k+1 is moved into phase k (post-B2, pre-gates), so the L2
// round-trip hides under gates+publish+B3+flag+epilogue. The loop top keeps
// only the vmcnt(0) wait + sH write. Everything else (gates placement, flag
// scheme value t+2 / poll t+1 with 2-phase slack, 3 barriers, epilogue, tail)
// is byte-identical to r1. hv[6] lives across the loop boundary (+~14 VGPR).
// Correctness of the early poll/issue: phase k+1 reads h_t' set s', published
// by members' gates at their phase k-1 (flag t'+1 posted there) -> the poll at
// our phase k post-B2 still has >=1 phase of slack; our own flag for s' was
// posted at our k-1. The acquire fence in poll_flags precedes the sc0 issue.
__device__ __forceinline__ void poll_flags(unsigned midx, unsigned val) {
  int tries = 0;
  for (;;) {
    unsigned v = __hip_atomic_load(&g_flag[midx], __ATOMIC_RELAXED, __HIP_MEMORY_SCOPE_AGENT);
    if (__ballot(v >= val) == ~0ull) break;
    if (++tries > (1<<18)) break;               // fail-visible, never hang
    if (tries > 8) __builtin_amdgcn_s_sleep(1);
  }
  __builtin_amdgcn_fence(__ATOMIC_ACQUIRE, "workgroup");
}

__global__ __launch_bounds__(256, 1) void k_gru(
    const float* __restrict__ Xc,
    const float* __restrict__ Wih, const float* __restrict__ Whh,
    const float* __restrict__ bih, const float* __restrict__ bhh,
    const float* __restrict__ wraww, const float* __restrict__ wrawb,
    const float* __restrict__ regemb, const float* __restrict__ bias,
    const float* __restrict__ h0,
    float* __restrict__ hillZ,       // = outw region (read until step t, then w_pos)
    float* __restrict__ hill,        // = outc region (read hill, overwrite contrib)
    float* __restrict__ outy)
{
  __shared__ __align__(16) bf16 sW2[32*WROW];   // 49,664 B : T2 rows(0-15) + T5 rows(16-31)
  __shared__ __align__(16) bf16 sH[16*768];     // 24,576 B : staged h for active set (swizzled)
  __shared__ float sGH2[2][16][100];            // 12,800 B : partial D per kt-half
  __shared__ float sGIN[16][32];                //  2,048 B : n-gate input part
  __shared__ float sHm[32][24];                 //  3,072 B (f32 master h slice)
  __shared__ float sBih[72], sBhh[72];          //    576 B
  __shared__ float sWrb[16];                    //     64 B
  __shared__ float sScal[2];                    //      8 B
  __shared__ unsigned sGP[2];                   //      8 B

  const int tid = threadIdx.x;
  const int wave = tid >> 6, lane = tid & 63;
  const int quad = lane >> 4, l16 = lane & 15;
  const int rg = wave & 1;
  const int kh = wave >> 1;

  // runtime group discovery: g = physical XCD
  if (tid == 0) {
    unsigned x;
    asm volatile("s_getreg_b32 %0, hwreg(HW_REG_XCC_ID, 0, 32)" : "=s"(x));
    x &= 7u;
    unsigned slot = __hip_atomic_fetch_add(&g_roster[x], 1u,
                        __ATOMIC_RELAXED, __HIP_MEMORY_SCOPE_AGENT);
    if (slot < 32u)
      __hip_atomic_store(&g_members[x*32u + slot], (unsigned)blockIdx.x,
                         __ATOMIC_RELAXED, __HIP_MEMORY_SCOPE_AGENT);
    sGP[0] = x; sGP[1] = slot & 31u;
    __hip_atomic_fetch_add(&g_sync, 1u, __ATOMIC_RELEASE, __HIP_MEMORY_SCOPE_AGENT);
    int tries = 0;
    while (__hip_atomic_load(&g_sync, __ATOMIC_ACQUIRE, __HIP_MEMORY_SCOPE_AGENT) < 256u) {
      if (++tries > (1<<20)) break;
      __builtin_amdgcn_s_sleep(1);
    }
  }
  __syncthreads();
  const int g = (int)sGP[0], p = (int)sGP[1];
  const int j0 = p*24;
  const int s_own = (p >= 16) ? 1 : 0;          // which set owns batch bq
  const int bqL = p & 15;                       // bq's row within its set's M-tile
  const int bq = g*32 + p;
  const unsigned member = __hip_atomic_load(&g_members[g*32 + (lane & 31)],
                              __ATOMIC_RELAXED, __HIP_MEMORY_SCOPE_AGENT);
  const unsigned midx0 = member * 64u;          // +s*32 selects the set's flag line
  const unsigned myflag = (unsigned)blockIdx.x * 64u;

  // ---- stage sW2: rows 0..15 = local rows 32..47 (T2), 16..31 = local 80..95 (T5)
  for (int c = tid; c < 32*192; c += 256) {
    int rl = c / 192, off = (c - rl*192)*4;
    int L = (rl < 16) ? (32 + rl) : (64 + rl);  // rl>=16 -> 80 + (rl-16)
    f32x4 w;
    if (L < 72)      w = *(const f32x4*)&Whh[(size_t)((L/24)*768 + j0 + (L%24))*768 + off];
    else if (L < 88) w = *(const f32x4*)&wraww[(size_t)(L-72)*768 + off];
    else             { w[0]=0.f; w[1]=0.f; w[2]=0.f; w[3]=0.f; }
    bf16x4 v; v[0]=(bf16)w[0]; v[1]=(bf16)w[1]; v[2]=(bf16)w[2]; v[3]=(bf16)w[3];
    *(bf16x4*)&sW2[rl*WROW + off] = v;
  }
  if (tid < 72) {
    int grow = (tid/24)*768 + j0 + (tid%24);
    sBih[tid] = bih[grow];
    sBhh[tid] = bhh[grow];
  }
  if (tid >= 128 && tid < 144) sWrb[tid-128] = wrawb[tid-128];
  if (wave == 0) {
    float sacc = 0.f;
    for (int k = lane; k < 768; k += 64) sacc += regemb[k];  // reg_emb[0]
    #pragma unroll
    for (int off = 32; off; off >>= 1) sacc += __shfl_xor(sacc, off, 64);
    if (lane == 0) { sScal[0] = 0.3f*sacc; sScal[1] = bias[0]; }
  }

  // ---- per-wave t-invariant register weights ----
  // bw0 = tile (rg? T3:T0), bw1 = tile (rg? T4:T1), 12 kt each (kh half).
  bf16x8 bw0[12], bw1[12];
  {
    const int LA = (rg ? 48 : 0) + l16;               // < 72 always
    const int LB = (rg ? 64 : 16) + l16;              // rg1,l16>=8 -> head rows 72..79
    const float* rowA = Whh + (size_t)((LA/24)*768 + j0 + (LA%24))*768;
    const float* rowB = (LB < 72)
        ? (Whh + (size_t)((LB/24)*768 + j0 + (LB%24))*768)
        : (wraww + (size_t)(LB-72)*768);
    #pragma unroll
    for (int kk = 0; kk < 12; kk++) {
      const int col = (kh*12 + kk)*32 + quad*8;
      bw0[kk] = ld_bf8(rowA + col);
      bw1[kk] = ld_bf8(rowB + col);
    }
  }
  // Wih fragments (kh==0 waves only). Head rows (>=72) have no input -> zero.
  bf16x8 wf0, wf1, wf2;
  #pragma unroll
  for (int i = 0; i < 8; i++) { wf0[i]=(bf16)0.f; wf1[i]=(bf16)0.f; wf2[i]=(bf16)0.f; }
  if (kh == 0) {
    const int base = rg ? 48 : 0;
    {
      const int L = base + l16;                       // 0-15 or 48-63
      wf0 = ld_bf8(Wih + (size_t)((L/24)*768 + j0 + (L%24))*32 + quad*8);
    }
    {
      const int L = base + 16 + l16;                  // 16-31 or 64-79
      if (L < 72)
        wf1 = ld_bf8(Wih + (size_t)((L/24)*768 + j0 + (L%24))*32 + quad*8);
    }
    if (rg == 0) {
      const int L = 32 + l16;                         // 32-47
      wf2 = ld_bf8(Wih + (size_t)((L/24)*768 + j0 + (L%24))*32 + quad*8);
    }
  }

  // ---- init h (parity 0): f32 master + bf16 publish ----
  {
    unsigned* hb = (unsigned*)g_hbuf;
    for (int e = tid; e < 384; e += 256) {
      int b = e/12, j = (e - b*12)*2;
      float f0 = h0[j0+j], f1 = h0[j0+j+1];
      sHm[b][j] = f0; sHm[b][j+1] = f1;
      union { bf16 h[2]; unsigned u; } pk;
      pk.h[0] = (bf16)f0; pk.h[1] = (bf16)f1;
      hb[((size_t)(g*32+b)*H_N + j0 + j) >> 1] = pk.u;
    }
  }
  __syncthreads();   // drains init publishes (vmcnt(0)) + LDS staging
  if (tid == 0) {
    __hip_atomic_store(&g_flag[myflag],      1u, __ATOMIC_RELAXED, __HIP_MEMORY_SCOPE_AGENT);
    __hip_atomic_store(&g_flag[myflag + 32], 1u, __ATOMIC_RELAXED, __HIP_MEMORY_SCOPE_AGENT);
  }
  const float regt = sScal[0], bias0 = sScal[1];

  float wp0_r = 0.f, hl0_r = 0.f, ct0_r = 0.f;  // t=0 state (lanes tid<16)

  // pipelined volley registers (live across the loop boundary)
  bf16x8 hv[6];
  const bf16* hb_base = g_hbuf;
  const int swz = (l16 & 7) << 3;

  // prologue: poll + ISSUE volley for phase (t=0,s=0); wait happens at loop top
  {
    poll_flags(midx0, 1u);
    const bf16* hsrc = hb_base + (size_t)(g*32 + l16)*H_N + quad*8;
    #pragma unroll
    for (int j = 0; j < 6; j++) {
      asm volatile("global_load_dwordx4 %0, %1, off sc0"
                   : "=v"(hv[j]) : "v"(hsrc + (wave*6 + j)*32) : "memory");
    }
  }

  // prologue: prefetch x(0) and hill/ctrl(0)
  f32x4 xf0, xf1;
  xf0[0]=0.f; xf0[1]=0.f; xf0[2]=0.f; xf0[3]=0.f; xf1 = xf0;
  if (kh == 0) {
    const int gb0 = g*32 + l16;
    const float* hz = hillZ + (size_t)gb0*T_N*16;
    const float* xr = Xc    + (size_t)gb0*T_N*16;
    const float* src = (quad < 2) ? (hz + quad*8) : (xr + (quad-2)*8);
    xf0 = *(const f32x4*)src;
    xf1 = *(const f32x4*)(src + 4);
  }
  float hl_pf = 0.f, ct_pf = 0.f;
  if (tid < 16) {
    hl_pf = hill[(size_t)bq*T_N*16 + tid];
    if (tid == 0) ct_pf = g_ctrl[(size_t)bq*T_N];
  }

  int par = 0;
  #pragma unroll 1
  for (int t = 0; t < T_N; t++) {
    #pragma unroll 1
    for (int s = 0; s < 2; s++) {
      // ---- wait pipelined volley (issued last phase / prologue) ----
      asm volatile("s_waitcnt vmcnt(0)"
          : "+v"(hv[0]),"+v"(hv[1]),"+v"(hv[2]),"+v"(hv[3]),"+v"(hv[4]),"+v"(hv[5])
          :: "memory");
      {
        bf16* dst = &sH[l16*768];
        #pragma unroll
        for (int j = 0; j < 6; j++) {
          const int cv = wave*6 + j;
          *(bf16x8*)&dst[(cv*32 + quad*8) ^ swz] = hv[j];
        }
      }
      // build ax from last phase's x prefetch (kh0 waves)
      bf16x8 ax;
      if (kh == 0) {
        ax[0]=(bf16)xf0[0]; ax[1]=(bf16)xf0[1]; ax[2]=(bf16)xf0[2]; ax[3]=(bf16)xf0[3];
        ax[4]=(bf16)xf1[0]; ax[5]=(bf16)xf1[1]; ax[6]=(bf16)xf1[2]; ax[7]=(bf16)xf1[3];
      }
      __syncthreads();   // B1: volley visible to all waves
      f32x4 a0; a0[0]=0.f; a0[1]=0.f; a0[2]=0.f; a0[3]=0.f;
      f32x4 a1 = a0, a2 = a0, gi0 = a0, gi1 = a0;
      if (kh == 0) {
        if (rg == 0) {   // r,z rows: fold input into hidden accumulators
          a0 = MFMA16(ax, wf0, a0);
          a1 = MFMA16(ax, wf1, a1);
          a2 = MFMA16(ax, wf2, a2);
        } else {         // n rows: input kept separate (needed for r*hn)
          gi0 = MFMA16(ax, wf0, gi0);
          gi1 = MFMA16(ax, wf1, gi1);
        }
      }
      // prefetch x for next phase (hides under MFMA burst)
      if (kh == 0) {
        const int sn = s ^ 1;
        int tn = (s == 1) ? t + 1 : t;
        if (tn >= T_N) tn = T_N - 1;
        const int gbn = g*32 + sn*16 + l16;
        const float* hz = hillZ + ((size_t)gbn*T_N + tn)*16;
        const float* xr = Xc    + ((size_t)gbn*T_N + tn)*16;
        const float* src = (quad < 2) ? (hz + quad*8) : (xr + (quad-2)*8);
        xf0 = *(const f32x4*)src;
        xf1 = *(const f32x4*)(src + 4);
      }
      // gh += h @ W_hh^T over this wave's kt half
      {
        const bf16* hrow = &sH[l16*768];
        const int rl3 = (rg ? 16 : 0) + l16;
        #pragma unroll
        for (int kk = 0; kk < 12; kk++) {
          const int kt = kh*12 + kk;
          bf16x8 ha = *(const bf16x8*)&hrow[(kt*32 + quad*8) ^ swz];
          a0 = MFMA16(ha, bw0[kk], a0);
          a1 = MFMA16(ha, bw1[kk], a1);
          a2 = MFMA16(ha, *(const bf16x8*)&sW2[rl3*WROW + kt*32 + quad*8], a2);
        }
      }
      // stage D fragments (partial sums per kt-half)
      {
        const int c0 = rg*48 + l16;
        #pragma unroll
        for (int r = 0; r < 4; r++) {
          const int rb = quad*4 + r;
          sGH2[kh][rb][c0]    = a0[r];
          sGH2[kh][rb][c0+16] = a1[r];
          sGH2[kh][rb][c0+32] = a2[r];
        }
        if (kh == 0 && rg == 1) {
          #pragma unroll
          for (int r = 0; r < 4; r++) {
            const int rb = quad*4 + r;
            sGIN[rb][l16]      = gi0[r];
            sGIN[rb][16 + l16] = gi1[r];
          }
        }
      }
      __syncthreads();   // B2: staging complete
      const bool own = (s_own == s);
      float hd_s = 0.f;
      if (own && tid < 16) hd_s = sGH2[0][bqL][72+tid] + sGH2[1][bqL][72+tid];
      // ---- PIPELINE: poll + ISSUE next phase's volley (hides RT under gates/B3) ----
      if (!(t == T_N - 1 && s == 1)) {
        const int sn2 = s ^ 1;
        const int tn2 = s ? (t + 1) : t;
        poll_flags(midx0 + (unsigned)(sn2*32), (unsigned)(tn2 + 1));
        const bf16* hsrc2 = hb_base + (size_t)(tn2 & 1)*B_N*H_N
                          + (size_t)(g*32 + sn2*16 + l16)*H_N + quad*8;
        #pragma unroll
        for (int j = 0; j < 6; j++) {
          asm volatile("global_load_dwordx4 %0, %1, off sc0"
                       : "=v"(hv[j]) : "v"(hsrc2 + (wave*6 + j)*32) : "memory");
        }
      }
      // gates -> h_new; f32 master feedback; plain-store publish (L2)
      if (tid >= 64) {
        const int e = tid - 64;                  // 0..191
        const int b = e / 12, jp = (e - b*12)*2;
        const int bg = s*16 + b;
        unsigned* hnxt = (unsigned*)(g_hbuf + (size_t)(1-par)*B_N*H_N);
        float hn0, hn1;
        {
          const int j = jp;
          float gh_r = sGH2[0][b][j]    + sGH2[1][b][j];
          float gh_z = sGH2[0][b][24+j] + sGH2[1][b][24+j];
          float gh_n = sGH2[0][b][48+j] + sGH2[1][b][48+j];
          float rr = sigmoidf_(gh_r + sBih[j]    + sBhh[j]);
          float zz = sigmoidf_(gh_z + sBih[24+j] + sBhh[24+j]);
          float nn = tanhf_(sGIN[b][j] + sBih[48+j] + rr*(gh_n + sBhh[48+j]));
          hn0 = (1.f-zz)*nn + zz*sHm[bg][j];
        }
        {
          const int j = jp + 1;
          float gh_r = sGH2[0][b][j]    + sGH2[1][b][j];
          float gh_z = sGH2[0][b][24+j] + sGH2[1][b][24+j];
          float gh_n = sGH2[0][b][48+j] + sGH2[1][b][48+j];
          float rr = sigmoidf_(gh_r + sBih[j]    + sBhh[j]);
          float zz = sigmoidf_(gh_z + sBih[24+j] + sBhh[24+j]);
          float nn = tanhf_(sGIN[b][j] + sBih[48+j] + rr*(gh_n + sBhh[48+j]));
          hn1 = (1.f-zz)*nn + zz*sHm[bg][j];
        }
        sHm[bg][jp] = hn0; sHm[bg][jp+1] = hn1;
        union { bf16 h[2]; unsigned w; } pk;
        pk.h[0] = (bf16)hn0; pk.h[1] = (bf16)hn1;
        hnxt[((size_t)(g*32+bg)*H_N + j0 + jp) >> 1] = pk.w;
      }
      __syncthreads();   // B3: vmcnt(0) drains publishes (and prefetched volley) into L2
      if (tid == 0)
        __hip_atomic_store(&g_flag[myflag + s*32], (unsigned)(t + 2),
                           __ATOMIC_RELAXED, __HIP_MEMORY_SCOPE_AGENT);
      // ---- deferred epilogue for tt = t-1 (owning phase only) ----
      if (own) {
        if (t > 0 && tid < 16) {
          const int tt = t - 1;
          float wp = softplusf_(hd_s + sWrb[tid]);
          float hl = hl_pf;
          if (tt == 0) { wp0_r = wp; hl0_r = hl; ct0_r = ct_pf; }
          else {
            size_t o = (size_t)bq*T_N + tt;
            float cv = hl*wp;
            hillZ[o*16 + tid] = wp;
            hill[o*16 + tid]  = cv;
            float cs = cv;
            cs += __shfl_xor(cs, 8, 64);
            cs += __shfl_xor(cs, 4, 64);
            cs += __shfl_xor(cs, 2, 64);
            cs += __shfl_xor(cs, 1, 64);
            if (tid == 0) outy[o] = cs + ct_pf + regt + bias0;
            if (tt == 1) {
              float w0 = 0.5f*(wp + wp0_r);
              float c0v = hl0_r*w0;
              size_t o0 = (size_t)bq*T_N;
              hillZ[o0*16 + tid] = w0;
              hill[o0*16 + tid]  = c0v;
              float cs0 = c0v;
              cs0 += __shfl_xor(cs0, 8, 64);
              cs0 += __shfl_xor(cs0, 4, 64);
              cs0 += __shfl_xor(cs0, 2, 64);
              cs0 += __shfl_xor(cs0, 1, 64);
              if (tid == 0) outy[o0] = cs0 + ct0_r + regt + bias0;
            }
          }
        }
        if (tid < 16) {
          hl_pf = hill[((size_t)bq*T_N + t)*16 + tid];
          if (tid == 0) ct_pf = g_ctrl[(size_t)bq*T_N + t];
        }
      }
    }
    par ^= 1;
  }

  // ---- tail: head for tt = T-1 from h_T (own set; cold path) ----
  {
    const int s = s_own;
    poll_flags(midx0 + (unsigned)(s*32), (unsigned)(T_N + 1));
    const bf16* hsrc = hb_base + (size_t)par*B_N*H_N
                     + (size_t)(g*32 + s*16 + l16)*H_N + quad*8;
    bf16x8 hv2[6];
    #pragma unroll
    for (int j = 0; j < 6; j++) {
      asm volatile("global_load_dwordx4 %0, %1, off sc0"
                   : "=v"(hv2[j]) : "v"(hsrc + (wave*6 + j)*32) : "memory");
    }
    asm volatile("s_waitcnt vmcnt(0)"
        : "+v"(hv2[0]),"+v"(hv2[1]),"+v"(hv2[2]),"+v"(hv2[3]),"+v"(hv2[4]),"+v"(hv2[5])
        :: "memory");
    bf16* dst = &sH[l16*768];
    #pragma unroll
    for (int j = 0; j < 6; j++) {
      const int cv = wave*6 + j;
      *(bf16x8*)&dst[(cv*32 + quad*8) ^ swz] = hv2[j];
    }
  }
  __syncthreads();
  if (rg == 1) {
    f32x4 a1; a1[0]=0.f; a1[1]=0.f; a1[2]=0.f; a1[3]=0.f;
    f32x4 a2 = a1;
    const bf16* hrow = &sH[l16*768];
    const int rl3 = 16 + l16;
    #pragma unroll
    for (int kk = 0; kk < 12; kk++) {
      const int kt = kh*12 + kk;
      bf16x8 ha = *(const bf16x8*)&hrow[(kt*32 + quad*8) ^ swz];
      a1 = MFMA16(ha, bw1[kk], a1);
      a2 = MFMA16(ha, *(const bf16x8*)&sW2[rl3*WROW + kt*32 + quad*8], a2);
    }
    #pragma unroll
    for (int r = 0; r < 4; r++) {
      const int rb = quad*4 + r;
      sGH2[kh][rb][64 + l16] = a1[r];
      sGH2[kh][rb][80 + l16] = a2[r];
    }
  }
  __syncthreads();
  if (tid < 16) {
    const int tt = T_N - 1;
    float wp = softplusf_(sGH2[0][bqL][72+tid] + sGH2[1][bqL][72+tid] + sWrb[tid]);
    float hl = hill[((size_t)bq*T_N + tt)*16 + tid];
    size_t o = (size_t)bq*T_N + tt;
    float cv = hl*wp;
    hillZ[o*16 + tid] = wp;
    hill[o*16 + tid]  = cv;
    float cs = cv;
    cs += __shfl_xor(cs, 8, 64);
    cs += __shfl_xor(cs, 4, 64);
    cs += __shfl_xor(cs, 2, 64);
    cs += __shfl_xor(cs, 1, 64);
    if (tid == 0) outy[o] = cs + g_ctrl[o] + regt + bias0;
  }
}

extern "C" void kernel_launch(void* const* d_in, const int* in_sizes, int n_in,
                              void* d_out, int out_size, void* d_ws, size_t ws_size,
                              hipStream_t stream) {
  const float* Xm    = (const float*)d_in[0];
  const float* Xc    = (const float*)d_in[1];
  const float* Aw    = (const float*)d_in[3];
  const float* ew1   = (const float*)d_in[4];
  const float* eb1   = (const float*)d_in[5];
  const float* ew2   = (const float*)d_in[6];
  const float* eb2   = (const float*)d_in[7];
  const float* nw    = (const float*)d_in[8];
  const float* nb    = (const float*)d_in[9];
  const float* Wih   = (const float*)d_in[10];
  const float* Whh   = (const float*)d_in[11];
  const float* bih   = (const float*)d_in[12];
  const float* bhh   = (const float*)d_in[13];
  const float* wraww = (const float*)d_in[14];
  const float* wrawb = (const float*)d_in[15];
  const float* alpha = (const float*)d_in[16];
  const float* hilla = (const float*)d_in[17];
  const float* hillg = (const float*)d_in[18];
  const float* cw    = (const float*)d_in[19];
  const float* cb    = (const float*)d_in[20];
  const float* regemb= (const float*)d_in[21];
  const float* bias  = (const float*)d_in[22];
  const float* h0    = (const float*)d_in[23];

  float* outy = (float*)d_out;
  float* outw = outy + 256*512;          // doubles as Z / hillZ scratch
  float* outc = outw + 256*512*16;       // doubles as hill scratch

  k_zero<<<1, 256, 0, stream>>>();
  k_encode<<<512, 256, 0, stream>>>(Xm, Xc, Aw, ew1, eb1, ew2, eb2, nw, nb, cw, cb,
                                    outw);
  k_adstock<<<64, 64, 0, stream>>>(Xm, alpha, hilla, hillg, outw, outc);
  // Plain launch: grid==256 CUs + ~93KB LDS (1 blk/CU) => all blocks co-resident.
  k_gru<<<dim3(256), dim3(256), 0, stream>>>(
      Xc, Wih, Whh, bih, bhh, wraww, wrawb, regemb, bias, h0,
      outw, outc, outy);
}

// Round 8
// 2969.778 us; speedup vs baseline: 1.4435x; 1.0206x over previous
//
#include <hip/hip_runtime.h>

typedef __bf16 bf16;
typedef bf16 bf16x8 __attribute__((ext_vector_type(8)));
typedef bf16 bf16x4 __attribute__((ext_vector_type(4)));
typedef float f32x4 __attribute__((ext_vector_type(4)));

#define MFMA16(a,b,c) __builtin_amdgcn_mfma_f32_16x16x32_bf16((a),(b),(c),0,0,0)

#define B_N 256
#define T_N 512
#define H_N 768
#define WROW 776      // 768 + 8 pad (bf16 elems)

// ---- device-global scratch (BSS) ----
__device__ float    g_ctrl[B_N * T_N];          // 512 KB
__device__ bf16     g_hbuf[2 * B_N * H_N];      // 768 KB (bf16 h exchange, intra-XCD L2)
__device__ unsigned g_flag[256 * 64];           // per-(block,set) flag, 128B apart
__device__ unsigned g_members[8 * 32];          // XCD roster -> blockIdx table
__device__ unsigned g_roster[8];
__device__ unsigned g_sync;

__device__ __forceinline__ float sigmoidf_(float x){ return 1.f/(1.f+__expf(-x)); }
__device__ __forceinline__ float tanhf_(float x){
  float e = __expf(-2.f*fabsf(x));
  float t = (1.f-e)/(1.f+e);
  return copysignf(t, x);
}
__device__ __forceinline__ float softplusf_(float x){
  return x > 20.f ? x : log1pf(__expf(x));
}
__device__ __forceinline__ bf16x8 ld_bf8(const float* p){
  f32x4 a = *(const f32x4*)p;
  f32x4 b = *(const f32x4*)(p + 4);
  bf16x8 v;
  v[0]=(bf16)a[0]; v[1]=(bf16)a[1]; v[2]=(bf16)a[2]; v[3]=(bf16)a[3];
  v[4]=(bf16)b[0]; v[5]=(bf16)b[1]; v[6]=(bf16)b[2]; v[7]=(bf16)b[3];
  return v;
}

__global__ void k_zero() {
  const int tid = threadIdx.x;
  for (int i = tid; i < 256*64; i += 256) g_flag[i] = 0u;
  if (tid < 256) g_members[tid] = 0u;   // fallback: block 0's flags (always advance)
  if (tid < 8)   g_roster[tid] = 0u;
  if (tid == 0)  g_sync = 0u;
}

// ---------------- kernel A: causal encoder Z + ctrl term (unchanged) ----------------
__global__ __launch_bounds__(256) void k_encode(
    const float* __restrict__ Xm, const float* __restrict__ Xc,
    const float* __restrict__ Aw,
    const float* __restrict__ ew1, const float* __restrict__ eb1,
    const float* __restrict__ ew2, const float* __restrict__ eb2,
    const float* __restrict__ nw,  const float* __restrict__ nb,
    const float* __restrict__ cw,  const float* __restrict__ cb,
    float* __restrict__ Zout)
{
  __shared__ float sA[16][16], sE1[16][32], sE2[16][16], sNW[16][32];
  __shared__ float sEB1[16], sEB2[16], sNB[16];
  __shared__ float sCW[768][16];
  __shared__ float sCB[768];
  const int tid = threadIdx.x;
  for (int i = tid; i < 256; i += 256) sA[i>>4][i&15] = Aw[i];
  for (int i = tid; i < 512; i += 256) sE1[i>>5][i&31] = ew1[i];
  for (int i = tid; i < 256; i += 256) sE2[i>>4][i&15] = ew2[i];
  for (int i = tid; i < 512; i += 256) sNW[i>>5][i&31] = nw[i];
  if (tid < 16) { sEB1[tid]=eb1[tid]; sEB2[tid]=eb2[tid]; sNB[tid]=nb[tid]; }
  for (int i = tid; i < 768*16; i += 256) sCW[i>>4][i&15] = cw[i];
  for (int i = tid; i < 768; i += 256) sCB[i] = cb[i];
  __syncthreads();
  const int idx = blockIdx.x*256 + tid;           // flat (b*T + t)
  const float* xmp = Xm + (size_t)idx*16;
  const float* xcp = Xc + (size_t)idx*16;
  float xm[16], xc[16];
  #pragma unroll
  for (int j=0;j<4;j++){
    *(f32x4*)&xm[j*4] = *(const f32x4*)(xmp + j*4);
    *(f32x4*)&xc[j*4] = *(const f32x4*)(xcp + j*4);
  }
  float snd[16], rcv[16];
  #pragma unroll
  for (int i=0;i<16;i++){
    float s=0.f, r=0.f;
    #pragma unroll
    for (int j=0;j<16;j++){ s += xm[j]*sA[i][j]; r += xm[j]*sA[j][i]; }
    snd[i]=s; rcv[i]=r;
  }
  float he[16];
  #pragma unroll
  for (int i=0;i<16;i++){
    float a = sEB1[i];
    #pragma unroll
    for (int k=0;k<16;k++) a += snd[k]*sE1[i][k];
    #pragma unroll
    for (int k=0;k<16;k++) a += rcv[k]*sE1[i][16+k];
    he[i] = fmaxf(a, 0.f);
  }
  float he2[16];
  #pragma unroll
  for (int i=0;i<16;i++){
    float a = sEB2[i];
    #pragma unroll
    for (int k=0;k<16;k++) a += he[k]*sE2[i][k];
    he2[i] = fmaxf(a, 0.f);
  }
  float* zp = Zout + (size_t)idx*16;
  #pragma unroll
  for (int m=0;m<16;m++){
    float a = sNB[m];
    #pragma unroll
    for (int k=0;k<16;k++) a += xm[k]*sNW[m][k];
    #pragma unroll
    for (int k=0;k<16;k++) a += he2[k]*sNW[m][16+k];
    zp[m] = fmaxf(a, 0.f);
  }
  float cs = 0.f;
  for (int i=0;i<768;i++){
    float a = sCB[i];
    #pragma unroll
    for (int k=0;k<16;k++) a += xc[k]*sCW[i][k];
    cs += fmaxf(a, 0.f);
  }
  g_ctrl[idx] = cs * 0.3f;
}

// ---------------- kernel B: adstock scan + hill + gru-input (unchanged) ----------------
__global__ __launch_bounds__(64) void k_adstock(
    const float* __restrict__ Xm, const float* __restrict__ alpha,
    const float* __restrict__ hill_a, const float* __restrict__ hill_g,
    float* __restrict__ Zio, float* __restrict__ hill_out)
{
  const int gid = blockIdx.x*64 + threadIdx.x;   // (b, m)
  const int b = gid >> 4, m = gid & 15;
  float a  = fminf(fmaxf(alpha[m],  0.f),  1.f);
  float ha = fminf(fmaxf(hill_a[m], 0.1f), 3.f);
  float hg = fminf(fmaxf(hill_g[m], 0.1f), 2.f);
  float gpow = __powf(hg, ha);
  const float* xp = Xm + (size_t)b*T_N*16 + m;
  float prev = 0.f, cmax = 0.f;
  for (int t=0;t<T_N;t++){ float x = xp[(size_t)t*16]; prev = x + a*prev; cmax = fmaxf(cmax, prev); }
  cmax = fmaxf(cmax, 1e-6f);
  float inv = 1.f/cmax;
  prev = 0.f;
  float* zp  = Zio      + (size_t)b*T_N*16 + m;
  float* hp  = hill_out + (size_t)b*T_N*16 + m;
  for (int t=0;t<T_N;t++){
    float x = xp[(size_t)t*16];
    prev = x + a*prev;
    float xn  = fmaxf(prev*inv, 0.f);
    float num = __powf(xn, ha);
    float h   = num / (num + gpow + 1e-8f);
    float z   = zp[(size_t)t*16];
    hp[(size_t)t*16] = h;
    zp[(size_t)t*16] = h + z;
  }
}

// ---------------- kernel C: persistent GRU + fused heads ----------------
// r8: BOTH sets per phase on a 512-thread block (8 waves = 2 squads of 4).
// Squad sq handles set sq; each squad runs the r7-proven 4-wave phase body
// (rg/kh tiling identical). 2 waves/SIMD -> latencies co-scheduled (m114).
// 512 phases (one per timestep) instead of 1024. Flags: per-set line,
// per-gate-wave vmcnt(0)+fetch_add(+1) (3 adds/set); pollers need 3*(t+1).
// Poll+volley-issue for t+1 at phase tail, post-B3, post-own-flags (no
// deadlock; zero-slack group sync accepted). LDS ~132 KB, 1 blk/CU.
__device__ __forceinline__ void poll_flags(unsigned midx, unsigned val) {
  int tries = 0;
  for (;;) {
    unsigned v = __hip_atomic_load(&g_flag[midx], __ATOMIC_RELAXED, __HIP_MEMORY_SCOPE_AGENT);
    if (__ballot(v >= val) == ~0ull) break;
    if (++tries > (1<<18)) break;               // fail-visible, never hang
    if (tries > 8) __builtin_amdgcn_s_sleep(1);
  }
  __builtin_amdgcn_fence(__ATOMIC_ACQUIRE, "workgroup");
}

__global__ __launch_bounds__(512, 1) void k_gru(
    const float* __restrict__ Xc,
    const float* __restrict__ Wih, const float* __restrict__ Whh,
    const float* __restrict__ bih, const float* __restrict__ bhh,
    const float* __restrict__ wraww, const float* __restrict__ wrawb,
    const float* __restrict__ regemb, const float* __restrict__ bias,
    const float* __restrict__ h0,
    float* __restrict__ hillZ,       // = outw region (read until step t, then w_pos)
    float* __restrict__ hill,        // = outc region (read hill, overwrite contrib)
    float* __restrict__ outy)
{
  __shared__ __align__(16) bf16 sW2[32*WROW];       // 49,664 B : T2 + T5 (shared by squads)
  __shared__ __align__(16) bf16 sH[2][16*768];      // 49,152 B : per-set staged h (swizzled)
  __shared__ float sGH2[2][2][16][100];             // 25,600 B : D partials [set][kh]
  __shared__ float sGIN[2][16][32];                 //  4,096 B : n-gate input part per set
  __shared__ float sHm[32][24];                     //  3,072 B : f32 master h (both sets)
  __shared__ float sBih[72], sBhh[72];              //    576 B
  __shared__ float sWrb[16];                        //     64 B
  __shared__ float sScal[2];
  __shared__ unsigned sGP[2];

  const int tid = threadIdx.x;
  const int wave = tid >> 6, lane = tid & 63;
  const int quad = lane >> 4, l16 = lane & 15;
  const int sq = wave >> 2;        // squad = set
  const int wv = wave & 3;         // wave-in-squad
  const int rg = wv & 1;
  const int kh = wv >> 1;

  // runtime group discovery: g = physical XCD
  if (tid == 0) {
    unsigned x;
    asm volatile("s_getreg_b32 %0, hwreg(HW_REG_XCC_ID, 0, 32)" : "=s"(x));
    x &= 7u;
    unsigned slot = __hip_atomic_fetch_add(&g_roster[x], 1u,
                        __ATOMIC_RELAXED, __HIP_MEMORY_SCOPE_AGENT);
    if (slot < 32u)
      __hip_atomic_store(&g_members[x*32u + slot], (unsigned)blockIdx.x,
                         __ATOMIC_RELAXED, __HIP_MEMORY_SCOPE_AGENT);
    sGP[0] = x; sGP[1] = slot & 31u;
    __hip_atomic_fetch_add(&g_sync, 1u, __ATOMIC_RELEASE, __HIP_MEMORY_SCOPE_AGENT);
    int tries = 0;
    while (__hip_atomic_load(&g_sync, __ATOMIC_ACQUIRE, __HIP_MEMORY_SCOPE_AGENT) < 256u) {
      if (++tries > (1<<20)) break;
      __builtin_amdgcn_s_sleep(1);
    }
  }
  __syncthreads();
  const int g = (int)sGP[0], p = (int)sGP[1];
  const int j0 = p*24;
  const int s_own = (p >= 16) ? 1 : 0;          // which set owns batch bq
  const int bqL = p & 15;
  const int bq = g*32 + p;
  const unsigned member = __hip_atomic_load(&g_members[g*32 + (lane & 31)],
                              __ATOMIC_RELAXED, __HIP_MEMORY_SCOPE_AGENT);
  const unsigned midx0 = member * 64u;          // +set*32 selects the set's flag line
  const unsigned myflag = (unsigned)blockIdx.x * 64u;

  // ---- stage sW2: rows 0..15 = local rows 32..47 (T2), 16..31 = local 80..95 (T5)
  for (int c = tid; c < 32*192; c += 512) {
    int rl = c / 192, off = (c - rl*192)*4;
    int L = (rl < 16) ? (32 + rl) : (64 + rl);
    f32x4 w;
    if (L < 72)      w = *(const f32x4*)&Whh[(size_t)((L/24)*768 + j0 + (L%24))*768 + off];
    else if (L < 88) w = *(const f32x4*)&wraww[(size_t)(L-72)*768 + off];
    else             { w[0]=0.f; w[1]=0.f; w[2]=0.f; w[3]=0.f; }
    bf16x4 v; v[0]=(bf16)w[0]; v[1]=(bf16)w[1]; v[2]=(bf16)w[2]; v[3]=(bf16)w[3];
    *(bf16x4*)&sW2[rl*WROW + off] = v;
  }
  if (tid < 72) {
    int grow = (tid/24)*768 + j0 + (tid%24);
    sBih[tid] = bih[grow];
    sBhh[tid] = bhh[grow];
  }
  if (tid >= 128 && tid < 144) sWrb[tid-128] = wrawb[tid-128];
  if (wave == 0) {
    float sacc = 0.f;
    for (int k = lane; k < 768; k += 64) sacc += regemb[k];  // reg_emb[0]
    #pragma unroll
    for (int off = 32; off; off >>= 1) sacc += __shfl_xor(sacc, off, 64);
    if (lane == 0) { sScal[0] = 0.3f*sacc; sScal[1] = bias[0]; }
  }

  // ---- per-wave t-invariant register weights (same for both squads) ----
  bf16x8 bw0[12], bw1[12];
  {
    const int LA = (rg ? 48 : 0) + l16;
    const int LB = (rg ? 64 : 16) + l16;
    const float* rowA = Whh + (size_t)((LA/24)*768 + j0 + (LA%24))*768;
    const float* rowB = (LB < 72)
        ? (Whh + (size_t)((LB/24)*768 + j0 + (LB%24))*768)
        : (wraww + (size_t)(LB-72)*768);
    #pragma unroll
    for (int kk = 0; kk < 12; kk++) {
      const int col = (kh*12 + kk)*32 + quad*8;
      bw0[kk] = ld_bf8(rowA + col);
      bw1[kk] = ld_bf8(rowB + col);
    }
  }
  // Wih fragments (kh==0 waves of each squad)
  bf16x8 wf0, wf1, wf2;
  #pragma unroll
  for (int i = 0; i < 8; i++) { wf0[i]=(bf16)0.f; wf1[i]=(bf16)0.f; wf2[i]=(bf16)0.f; }
  if (kh == 0) {
    const int base = rg ? 48 : 0;
    {
      const int L = base + l16;
      wf0 = ld_bf8(Wih + (size_t)((L/24)*768 + j0 + (L%24))*32 + quad*8);
    }
    {
      const int L = base + 16 + l16;
      if (L < 72)
        wf1 = ld_bf8(Wih + (size_t)((L/24)*768 + j0 + (L%24))*32 + quad*8);
    }
    if (rg == 0) {
      const int L = 32 + l16;
      wf2 = ld_bf8(Wih + (size_t)((L/24)*768 + j0 + (L%24))*32 + quad*8);
    }
  }

  // ---- init h (parity 0): f32 master + bf16 publish ----
  {
    unsigned* hb = (unsigned*)g_hbuf;
    for (int e = tid; e < 384; e += 512) {
      int b = e/12, j = (e - b*12)*2;
      float f0 = h0[j0+j], f1 = h0[j0+j+1];
      sHm[b][j] = f0; sHm[b][j+1] = f1;
      union { bf16 h[2]; unsigned u; } pk;
      pk.h[0] = (bf16)f0; pk.h[1] = (bf16)f1;
      hb[((size_t)(g*32+b)*H_N + j0 + j) >> 1] = pk.u;
    }
  }
  __syncthreads();   // drains init publishes (vmcnt(0)) + LDS staging
  if (tid == 0) {
    __hip_atomic_store(&g_flag[myflag],      3u, __ATOMIC_RELAXED, __HIP_MEMORY_SCOPE_AGENT);
    __hip_atomic_store(&g_flag[myflag + 32], 3u, __ATOMIC_RELAXED, __HIP_MEMORY_SCOPE_AGENT);
  }
  const float regt = sScal[0], bias0 = sScal[1];

  float wp0_r = 0.f, hl0_r = 0.f, ct0_r = 0.f;  // t=0 state (lanes tid<16)

  // pipelined volley regs (live across phase boundary)
  bf16x8 hv[6];
  const bf16* hb_base = g_hbuf;
  const int swz = (l16 & 7) << 3;

  // prologue: poll + ISSUE volley for t=0 (own set)
  {
    poll_flags(midx0 + (unsigned)(sq*32), 3u);
    const bf16* hsrc = hb_base + (size_t)(g*32 + sq*16 + l16)*H_N + quad*8;
    #pragma unroll
    for (int j = 0; j < 6; j++) {
      asm volatile("global_load_dwordx4 %0, %1, off sc0"
                   : "=v"(hv[j]) : "v"(hsrc + (wv*6 + j)*32) : "memory");
    }
  }

  // prologue: prefetch x(0) for own set (kh0 waves) and hill/ctrl(0) (wave0)
  f32x4 xf0, xf1;
  xf0[0]=0.f; xf0[1]=0.f; xf0[2]=0.f; xf0[3]=0.f; xf1 = xf0;
  if (kh == 0) {
    const int gb0 = g*32 + sq*16 + l16;
    const float* hz = hillZ + (size_t)gb0*T_N*16;
    const float* xr = Xc    + (size_t)gb0*T_N*16;
    const float* src = (quad < 2) ? (hz + quad*8) : (xr + (quad-2)*8);
    xf0 = *(const f32x4*)src;
    xf1 = *(const f32x4*)(src + 4);
  }
  float hl_pf = 0.f, ct_pf = 0.f;
  if (tid < 16) {
    hl_pf = hill[(size_t)bq*T_N*16 + tid];
    if (tid == 0) ct_pf = g_ctrl[(size_t)bq*T_N];
  }

  #pragma unroll 1
  for (int t = 0; t < T_N; t++) {
    // ---- wait pipelined volley; write sH[sq] ----
    asm volatile("s_waitcnt vmcnt(0)"
        : "+v"(hv[0]),"+v"(hv[1]),"+v"(hv[2]),"+v"(hv[3]),"+v"(hv[4]),"+v"(hv[5])
        :: "memory");
    {
      bf16* dst = &sH[sq][l16*768];
      #pragma unroll
      for (int j = 0; j < 6; j++) {
        const int cv = wv*6 + j;
        *(bf16x8*)&dst[(cv*32 + quad*8) ^ swz] = hv[j];
      }
    }
    // build ax from last step's x prefetch (kh0 waves)
    bf16x8 ax;
    if (kh == 0) {
      ax[0]=(bf16)xf0[0]; ax[1]=(bf16)xf0[1]; ax[2]=(bf16)xf0[2]; ax[3]=(bf16)xf0[3];
      ax[4]=(bf16)xf1[0]; ax[5]=(bf16)xf1[1]; ax[6]=(bf16)xf1[2]; ax[7]=(bf16)xf1[3];
    }
    __syncthreads();   // B1: volleys visible
    f32x4 a0; a0[0]=0.f; a0[1]=0.f; a0[2]=0.f; a0[3]=0.f;
    f32x4 a1 = a0, a2 = a0, gi0 = a0, gi1 = a0;
    if (kh == 0) {
      if (rg == 0) {   // r,z rows: fold input into hidden accumulators
        a0 = MFMA16(ax, wf0, a0);
        a1 = MFMA16(ax, wf1, a1);
        a2 = MFMA16(ax, wf2, a2);
      } else {         // n rows: input kept separate
        gi0 = MFMA16(ax, wf0, gi0);
        gi1 = MFMA16(ax, wf1, gi1);
      }
    }
    // prefetch x(t+1) for own set (kh0 waves; hides under MFMA burst)
    if (kh == 0) {
      int tn = t + 1; if (tn >= T_N) tn = T_N - 1;
      const int gbn = g*32 + sq*16 + l16;
      const float* hz = hillZ + ((size_t)gbn*T_N + tn)*16;
      const float* xr = Xc    + ((size_t)gbn*T_N + tn)*16;
      const float* src = (quad < 2) ? (hz + quad*8) : (xr + (quad-2)*8);
      xf0 = *(const f32x4*)src;
      xf1 = *(const f32x4*)(src + 4);
    }
    // gh += h @ W_hh^T over this wave's kt half (set sq)
    {
      const bf16* hrow = &sH[sq][l16*768];
      const int rl3 = (rg ? 16 : 0) + l16;
      #pragma unroll
      for (int kk = 0; kk < 12; kk++) {
        const int kt = kh*12 + kk;
        bf16x8 ha = *(const bf16x8*)&hrow[(kt*32 + quad*8) ^ swz];
        a0 = MFMA16(ha, bw0[kk], a0);
        a1 = MFMA16(ha, bw1[kk], a1);
        a2 = MFMA16(ha, *(const bf16x8*)&sW2[rl3*WROW + kt*32 + quad*8], a2);
      }
    }
    // stage D fragments (per-set, per-kh partials)
    {
      const int c0 = rg*48 + l16;
      #pragma unroll
      for (int r = 0; r < 4; r++) {
        const int rb = quad*4 + r;
        sGH2[sq][kh][rb][c0]    = a0[r];
        sGH2[sq][kh][rb][c0+16] = a1[r];
        sGH2[sq][kh][rb][c0+32] = a2[r];
      }
      if (kh == 0 && rg == 1) {
        #pragma unroll
        for (int r = 0; r < 4; r++) {
          const int rb = quad*4 + r;
          sGIN[sq][rb][l16]      = gi0[r];
          sGIN[sq][rb][16 + l16] = gi1[r];
        }
      }
    }
    __syncthreads();   // B2: staging complete
    float hd_s = 0.f;
    if (tid < 16) hd_s = sGH2[s_own][0][bqL][72+tid] + sGH2[s_own][1][bqL][72+tid];
    // ---- gates: waves wv=1..3 of EACH squad (384 threads total) ----
    if (wv != 0) {
      const int e = (wv - 1)*64 + lane;          // 0..191 within squad
      const int b = e / 12, jp = (e - b*12)*2;
      const int bg = sq*16 + b;
      unsigned* hnxt = (unsigned*)(g_hbuf + (size_t)((t+1)&1)*B_N*H_N);
      float hn0, hn1;
      {
        const int j = jp;
        float gh_r = sGH2[sq][0][b][j]    + sGH2[sq][1][b][j];
        float gh_z = sGH2[sq][0][b][24+j] + sGH2[sq][1][b][24+j];
        float gh_n = sGH2[sq][0][b][48+j] + sGH2[sq][1][b][48+j];
        float rr = sigmoidf_(gh_r + sBih[j]    + sBhh[j]);
        float zz = sigmoidf_(gh_z + sBih[24+j] + sBhh[24+j]);
        float nn = tanhf_(sGIN[sq][b][j] + sBih[48+j] + rr*(gh_n + sBhh[48+j]));
        hn0 = (1.f-zz)*nn + zz*sHm[bg][j];
      }
      {
        const int j = jp + 1;
        float gh_r = sGH2[sq][0][b][j]    + sGH2[sq][1][b][j];
        float gh_z = sGH2[sq][0][b][24+j] + sGH2[sq][1][b][24+j];
        float gh_n = sGH2[sq][0][b][48+j] + sGH2[sq][1][b][48+j];
        float rr = sigmoidf_(gh_r + sBih[j]    + sBhh[j]);
        float zz = sigmoidf_(gh_z + sBih[24+j] + sBhh[24+j]);
        float nn = tanhf_(sGIN[sq][b][j] + sBih[48+j] + rr*(gh_n + sBhh[48+j]));
        hn1 = (1.f-zz)*nn + zz*sHm[bg][j];
      }
      sHm[bg][jp] = hn0; sHm[bg][jp+1] = hn1;
      union { bf16 h[2]; unsigned w; } pk;
      pk.h[0] = (bf16)hn0; pk.h[1] = (bf16)hn1;
      hnxt[((size_t)(g*32+bg)*H_N + j0 + jp) >> 1] = pk.w;
      asm volatile("s_waitcnt vmcnt(0)" ::: "memory");   // wave-local drain
      if (lane == 0)
        __hip_atomic_fetch_add(&g_flag[myflag + sq*32], 1u,
                               __ATOMIC_RELAXED, __HIP_MEMORY_SCOPE_AGENT);
    }
    __syncthreads();   // B3: gates/publishes done; sGH2/sH reusable next step
    // ---- tail: poll + ISSUE next step's volley (own flags already posted) ----
    if (t < T_N - 1) {
      poll_flags(midx0 + (unsigned)(sq*32), 3u*(unsigned)(t + 2));
      const bf16* hsrc2 = hb_base + (size_t)((t+1)&1)*B_N*H_N
                        + (size_t)(g*32 + sq*16 + l16)*H_N + quad*8;
      #pragma unroll
      for (int j = 0; j < 6; j++) {
        asm volatile("global_load_dwordx4 %0, %1, off sc0"
                     : "=v"(hv[j]) : "v"(hsrc2 + (wv*6 + j)*32) : "memory");
      }
    }
    // ---- deferred epilogue for tt = t-1 (wave0, every step now) ----
    if (tid < 16) {
      if (t > 0) {
        const int tt = t - 1;
        float wp = softplusf_(hd_s + sWrb[tid]);
        float hl = hl_pf;
        if (tt == 0) { wp0_r = wp; hl0_r = hl; ct0_r = ct_pf; }
        else {
          size_t o = (size_t)bq*T_N + tt;
          float cv = hl*wp;
          hillZ[o*16 + tid] = wp;
          hill[o*16 + tid]  = cv;
          float cs = cv;
          cs += __shfl_xor(cs, 8, 64);
          cs += __shfl_xor(cs, 4, 64);
          cs += __shfl_xor(cs, 2, 64);
          cs += __shfl_xor(cs, 1, 64);
          if (tid == 0) outy[o] = cs + ct_pf + regt + bias0;
          if (tt == 1) {
            float w0 = 0.5f*(wp + wp0_r);
            float c0v = hl0_r*w0;
            size_t o0 = (size_t)bq*T_N;
            hillZ[o0*16 + tid] = w0;
            hill[o0*16 + tid]  = c0v;
            float cs0 = c0v;
            cs0 += __shfl_xor(cs0, 8, 64);
            cs0 += __shfl_xor(cs0, 4, 64);
            cs0 += __shfl_xor(cs0, 2, 64);
            cs0 += __shfl_xor(cs0, 1, 64);
            if (tid == 0) outy[o0] = cs0 + ct0_r + regt + bias0;
          }
        }
      }
      hl_pf = hill[((size_t)bq*T_N + t)*16 + tid];
      if (tid == 0) ct_pf = g_ctrl[(size_t)bq*T_N + t];
    }
  }

  // ---- tail: head for tt = T-1 from h_T (own set; cold path) ----
  {
    poll_flags(midx0 + (unsigned)(s_own*32), 3u*(unsigned)(T_N + 1));
    if (sq == s_own) {
      const bf16* hsrc = hb_base + (size_t)(T_N & 1)*B_N*H_N
                       + (size_t)(g*32 + s_own*16 + l16)*H_N + quad*8;
      bf16x8 hv2[6];
      #pragma unroll
      for (int j = 0; j < 6; j++) {
        asm volatile("global_load_dwordx4 %0, %1, off sc0"
                     : "=v"(hv2[j]) : "v"(hsrc + (wv*6 + j)*32) : "memory");
      }
      asm volatile("s_waitcnt vmcnt(0)"
          : "+v"(hv2[0]),"+v"(hv2[1]),"+v"(hv2[2]),"+v"(hv2[3]),"+v"(hv2[4]),"+v"(hv2[5])
          :: "memory");
      bf16* dst = &sH[s_own][l16*768];
      #pragma unroll
      for (int j = 0; j < 6; j++) {
        const int cv = wv*6 + j;
        *(bf16x8*)&dst[(cv*32 + quad*8) ^ swz] = hv2[j];
      }
    }
  }
  __syncthreads();
  if (sq == s_own && rg == 1) {
    f32x4 a1; a1[0]=0.f; a1[1]=0.f; a1[2]=0.f; a1[3]=0.f;
    f32x4 a2 = a1;
    const bf16* hrow = &sH[s_own][l16*768];
    const int rl3 = 16 + l16;
    #pragma unroll
    for (int kk = 0; kk < 12; kk++) {
      const int kt = kh*12 + kk;
      bf16x8 ha = *(const bf16x8*)&hrow[(kt*32 + quad*8) ^ swz];
      a1 = MFMA16(ha, bw1[kk], a1);
      a2 = MFMA16(ha, *(const bf16x8*)&sW2[rl3*WROW + kt*32 + quad*8], a2);
    }
    #pragma unroll
    for (int r = 0; r < 4; r++) {
      const int rb = quad*4 + r;
      sGH2[s_own][kh][rb][64 + l16] = a1[r];
      sGH2[s_own][kh][rb][80 + l16] = a2[r];
    }
  }
  __syncthreads();
  if (tid < 16) {
    const int tt = T_N - 1;
    float wp = softplusf_(sGH2[s_own][0][bqL][72+tid] + sGH2[s_own][1][bqL][72+tid]
                          + sWrb[tid]);
    float hl = hill[((size_t)bq*T_N + tt)*16 + tid];
    size_t o = (size_t)bq*T_N + tt;
    float cv = hl*wp;
    hillZ[o*16 + tid] = wp;
    hill[o*16 + tid]  = cv;
    float cs = cv;
    cs += __shfl_xor(cs, 8, 64);
    cs += __shfl_xor(cs, 4, 64);
    cs += __shfl_xor(cs, 2, 64);
    cs += __shfl_xor(cs, 1, 64);
    if (tid == 0) outy[o] = cs + g_ctrl[o] + regt + bias0;
  }
}

extern "C" void kernel_launch(void* const* d_in, const int* in_sizes, int n_in,
                              void* d_out, int out_size, void* d_ws, size_t ws_size,
                              hipStream_t stream) {
  const float* Xm    = (const float*)d_in[0];
  const float* Xc    = (const float*)d_in[1];
  const float* Aw    = (const float*)d_in[3];
  const float* ew1   = (const float*)d_in[4];
  const float* eb1   = (const float*)d_in[5];
  const float* ew2   = (const float*)d_in[6];
  const float* eb2   = (const float*)d_in[7];
  const float* nw    = (const float*)d_in[8];
  const float* nb    = (const float*)d_in[9];
  const float* Wih   = (const float*)d_in[10];
  const float* Whh   = (const float*)d_in[11];
  const float* bih   = (const float*)d_in[12];
  const float* bhh   = (const float*)d_in[13];
  const float* wraww = (const float*)d_in[14];
  const float* wrawb = (const float*)d_in[15];
  const float* alpha = (const float*)d_in[16];
  const float* hilla = (const float*)d_in[17];
  const float* hillg = (const float*)d_in[18];
  const float* cw    = (const float*)d_in[19];
  const float* cb    = (const float*)d_in[20];
  const float* regemb= (const float*)d_in[21];
  const float* bias  = (const float*)d_in[22];
  const float* h0    = (const float*)d_in[23];

  float* outy = (float*)d_out;
  float* outw = outy + 256*512;          // doubles as Z / hillZ scratch
  float* outc = outw + 256*512*16;       // doubles as hill scratch

  k_zero<<<1, 256, 0, stream>>>();
  k_encode<<<512, 256, 0, stream>>>(Xm, Xc, Aw, ew1, eb1, ew2, eb2, nw, nb, cw, cb,
                                    outw);
  k_adstock<<<64, 64, 0, stream>>>(Xm, alpha, hilla, hillg, outw, outc);
  // Plain launch: grid==256 CUs, 512 threads, ~132KB LDS (1 blk/CU, 2 waves/SIMD).
  k_gru<<<dim3(256), dim3(512), 0, stream>>>(
      Xc, Wih, Whh, bih, bhh, wraww, wrawb, regemb, bias, h0,
      outw, outc, outy);
}